// Round 6
// baseline (748.982 us; speedup 1.0000x reference)
//
#include <hip/hip_runtime.h>
#include <cstddef>
#include <cstdint>

#define NODES 65536      // B*N
#define NEDGE 1048576    // B*E_PER
#define NB    64
#define NPER  1024
#define TOPK  512
#define BKR   32768      // NB*TOPK
#define DIM   128
#define NM    ((size_t)NODES * DIM)   // floats per node-array

typedef float f32x4 __attribute__((ext_vector_type(4)));

__device__ __forceinline__ f32x4 ntload4(const f32x4* p) {
  return __builtin_nontemporal_load(p);
}
__device__ __forceinline__ void ntstore4(f32x4* p, f32x4 v) {
  __builtin_nontemporal_store(v, p);
}
__device__ __forceinline__ long long ntloadll(const long long* p) {
  return __builtin_nontemporal_load(p);
}
__device__ __forceinline__ float dotv(f32x4 a, f32x4 b) {
  return fmaf(a.x, b.x, fmaf(a.y, b.y, fmaf(a.z, b.z, a.w * b.w)));
}

// ================= shared GEMM core: Out[row0..row0+7] = A-rows @ sW + bias =============
__device__ __forceinline__ void gemm_core(
    const float* __restrict__ A, const f32x4* __restrict__ sW,
    const float* __restrict__ bias, float* __restrict__ Out,
    size_t row0, int ostride, int tc) {
  const float* a0 = A + row0 * 128;
  f32x4 acc0[8], acc1[8];
#pragma unroll
  for (int r = 0; r < 8; ++r) { acc0[r] = (f32x4)(0.f); acc1[r] = (f32x4)(0.f); }
#pragma unroll 4
  for (int k4 = 0; k4 < 32; ++k4) {
    f32x4 a[8];
#pragma unroll
    for (int r = 0; r < 8; ++r)
      a[r] = *reinterpret_cast<const f32x4*>(a0 + r * 128 + k4 * 4);
#pragma unroll
    for (int kk = 0; kk < 4; ++kk) {
      const f32x4 w0 = sW[(k4 * 4 + kk) * 32 + tc * 2];
      const f32x4 w1 = sW[(k4 * 4 + kk) * 32 + tc * 2 + 1];
#pragma unroll
      for (int r = 0; r < 8; ++r) {
        const float av = a[r][kk];
        acc0[r] += av * w0;
        acc1[r] += av * w1;
      }
    }
  }
  const f32x4 b0 = reinterpret_cast<const f32x4*>(bias)[tc * 2];
  const f32x4 b1 = reinterpret_cast<const f32x4*>(bias)[tc * 2 + 1];
#pragma unroll
  for (int r = 0; r < 8; ++r) {
    f32x4* outp = reinterpret_cast<f32x4*>(Out + (row0 + r) * (size_t)ostride + tc * 8);
    outp[0] = acc0[r] + b0;
    outp[1] = acc1[r] + b1;
  }
}

// 5 GEMMs in one launch, 512 threads, 256 rows/block; k,v interleaved into kv[*][256]
__global__ __launch_bounds__(512) void gemm_multi(
    const float* __restrict__ x,
    const float* __restrict__ Wq, const float* __restrict__ bq, float* __restrict__ q,
    const float* __restrict__ Wk, const float* __restrict__ bk,
    const float* __restrict__ Wv, const float* __restrict__ bv, float* __restrict__ kv,
    const float* __restrict__ Ws, const float* __restrict__ bs, float* __restrict__ sl,
    const float* __restrict__ Wc, const float* __restrict__ bc, float* __restrict__ qw) {
  __shared__ f32x4 sW[128 * 32];
  const int which = blockIdx.x >> 8;
  const int bid = blockIdx.x & 255;
  const int t = threadIdx.x;
  const float* W; const float* bias; float* Out; int ostride = 128;
  if (which == 0)      { W = Wq; bias = bq; Out = q; }
  else if (which == 1) { W = Wk; bias = bk; Out = kv;       ostride = 256; }
  else if (which == 2) { W = Wv; bias = bv; Out = kv + 128; ostride = 256; }
  else if (which == 3) { W = Ws; bias = bs; Out = sl; }
  else                 { W = Wc; bias = bc; Out = qw; }
  const f32x4* W4 = reinterpret_cast<const f32x4*>(W);
#pragma unroll
  for (int i = 0; i < 8; ++i) sW[t + i * 512] = W4[t + i * 512];
  __syncthreads();
  gemm_core(x, sW, bias, Out, (size_t)bid * 256 + (t >> 4) * 8, ostride, t & 15);
}

// ====== final GEMM: out = relu(agge@We + be + aggv + sl); outc + score epilogue ======
__global__ __launch_bounds__(256) void gemm_final(
    const float* __restrict__ A, const float* __restrict__ W,
    const float* __restrict__ bias, const float* __restrict__ aggv,
    const float* __restrict__ sl, const float* __restrict__ pwn,
    float* __restrict__ outc, float* __restrict__ score) {
  __shared__ f32x4 sW[128 * 32];
  const int t = threadIdx.x;
  const f32x4* W4 = reinterpret_cast<const f32x4*>(W);
#pragma unroll
  for (int i = 0; i < 16; ++i) sW[t + i * 256] = W4[t + i * 256];
  const int tc = t & 15;
  const size_t row0 = (size_t)blockIdx.x * 128 + (t >> 4) * 8;
  const float* a0 = A + row0 * 128;
  f32x4 acc0[8], acc1[8];
#pragma unroll
  for (int r = 0; r < 8; ++r) { acc0[r] = (f32x4)(0.f); acc1[r] = (f32x4)(0.f); }
  __syncthreads();
#pragma unroll 4
  for (int k4 = 0; k4 < 32; ++k4) {
    f32x4 a[8];
#pragma unroll
    for (int r = 0; r < 8; ++r)
      a[r] = *reinterpret_cast<const f32x4*>(a0 + r * 128 + k4 * 4);
#pragma unroll
    for (int kk = 0; kk < 4; ++kk) {
      const f32x4 w0 = sW[(k4 * 4 + kk) * 32 + tc * 2];
      const f32x4 w1 = sW[(k4 * 4 + kk) * 32 + tc * 2 + 1];
#pragma unroll
      for (int r = 0; r < 8; ++r) {
        const float av = a[r][kk];
        acc0[r] += av * w0;
        acc1[r] += av * w1;
      }
    }
  }
  const f32x4 b0 = reinterpret_cast<const f32x4*>(bias)[tc * 2];
  const f32x4 b1 = reinterpret_cast<const f32x4*>(bias)[tc * 2 + 1];
  const f32x4 p0 = reinterpret_cast<const f32x4*>(pwn)[tc * 2];
  const f32x4 p1 = reinterpret_cast<const f32x4*>(pwn)[tc * 2 + 1];
#pragma unroll
  for (int r = 0; r < 8; ++r) {
    const f32x4 v0 = reinterpret_cast<const f32x4*>(aggv + (row0 + r) * 128 + tc * 8)[0];
    const f32x4 v1 = reinterpret_cast<const f32x4*>(aggv + (row0 + r) * 128 + tc * 8)[1];
    const f32x4 s0 = reinterpret_cast<const f32x4*>(sl + (row0 + r) * 128 + tc * 8)[0];
    const f32x4 s1 = reinterpret_cast<const f32x4*>(sl + (row0 + r) * 128 + tc * 8)[1];
    f32x4 o0 = acc0[r] + b0 + v0 + s0;
    f32x4 o1 = acc1[r] + b1 + v1 + s1;
#pragma unroll
    for (int c = 0; c < 4; ++c) { o0[c] = fmaxf(o0[c], 0.f); o1[c] = fmaxf(o1[c], 0.f); }
    f32x4* outp = reinterpret_cast<f32x4*>(outc + (row0 + r) * 128 + tc * 8);
    outp[0] = o0; outp[1] = o1;
    float sp = dotv(o0, p0) + dotv(o1, p1);
#pragma unroll
    for (int d = 1; d < 16; d <<= 1) sp += __shfl_xor(sp, d, 16);
    if (tc == 0) score[row0 + r] = tanhf(sp);
  }
}

// ===== fused setup: init deg/nmap/bn2 + pwn + Wc[t,i]=sum_d Wq[t,d]*We[i,d] =====
__global__ __launch_bounds__(256) void setup_kernel(
    const float* __restrict__ pool_w, float* __restrict__ pwn,
    const float* __restrict__ Wq, const float* __restrict__ bq,
    const float* __restrict__ We, float* __restrict__ Wc, float* __restrict__ bc,
    int* __restrict__ deg, int* __restrict__ nmap, float* __restrict__ bn2) {
  const int blk = blockIdx.x;
  const int t = threadIdx.x;
  if (blk < 256) {                 // init
    const int i = blk * 256 + t;
    deg[i] = 0; nmap[i] = -1;
    if (i < 256) bn2[i] = 0.f;     // bnsum[128]+bnsq[128]
  } else if (blk == 256) {         // pool_w normalization
    __shared__ float red[128];
    if (t < 128) {
      const float vv = pool_w[t];
      red[t] = vv * vv;
    }
    __syncthreads();
    for (int d = 64; d > 0; d >>= 1) {
      if (t < d) red[t] += red[t + d];
      __syncthreads();
    }
    if (t < 128) pwn[t] = pool_w[t] * rsqrtf(red[0]);
  } else {                         // Wc: 2 output cols per block
    __shared__ float sWe[2][128];
    const int i = (blk - 257) * 2 + (t >> 7);   // output col
    const int tl = t & 127;
    sWe[t >> 7][tl] = We[i * 128 + tl];
    __syncthreads();
    float s = 0.f;
    for (int d = 0; d < 128; ++d) s = fmaf(Wq[tl * 128 + d], sWe[t >> 7][d], s);
    Wc[tl * 128 + i] = s;
    if (tl == 0) {
      float sb = 0.f;
      for (int d = 0; d < 128; ++d) sb = fmaf(bq[d], sWe[t >> 7][d], sb);
      bc[i] = sb;
    }
  }
}

// ---------------- CSR build ----------------
__global__ void deg_kernel(const int* __restrict__ dst, int* __restrict__ deg) {
  const int e = blockIdx.x * 256 + threadIdx.x;
  atomicAdd(&deg[dst[e]], 1);
}

__global__ __launch_bounds__(1024) void scan_kernel(const int* __restrict__ deg,
                                                    int* __restrict__ offs,
                                                    int* __restrict__ woff) {
  __shared__ int part[1024];
  const int t = threadIdx.x;
  const int base = t * 64;
  int s = 0;
  for (int j = 0; j < 64; ++j) s += deg[base + j];
  part[t] = s;
  __syncthreads();
  for (int d = 1; d < 1024; d <<= 1) {
    const int add = (t >= d) ? part[t - d] : 0;
    __syncthreads();
    part[t] += add;
    __syncthreads();
  }
  int run = part[t] - s;
  for (int j = 0; j < 64; ++j) {
    offs[base + j] = run; woff[base + j] = run;
    run += deg[base + j];
  }
  if (t == 1023) offs[NODES] = run;
}

// sorted edge array: packed (src<<32 | e)
__global__ void scatter_kernel(const int* __restrict__ dst, const int* __restrict__ src,
                               int* __restrict__ woff, long long* __restrict__ srt) {
  const int e = blockIdx.x * 256 + threadIdx.x;
  const int pos = atomicAdd(&woff[dst[e]], 1);
  srt[pos] = ((long long)src[e] << 32) | (unsigned)e;
}

// ========== fused attention: 4x16-lane groups per wave, 4 edges/group in flight ==========
// kv interleaved [node][256]; ea read with NONTEMPORAL loads (keep kv/q/qw L2-resident)
__global__ __launch_bounds__(256) void attn_v5(
    const float* __restrict__ q, const float* __restrict__ kv,
    const float* __restrict__ qw, const float* __restrict__ ea,
    const float* __restrict__ be, const long long* __restrict__ srt,
    const int* __restrict__ offs, float* __restrict__ aggv,
    float* __restrict__ agge) {
  int b = blockIdx.x;
  b = (b & 7) * 2048 + (b >> 3);                        // XCD-bijective swizzle (16384%8==0)
  const int wid = b * 4 + (threadIdx.x >> 6);
  const int lane = threadIdx.x & 63;
  const int g = lane >> 4;        // edge-group 0..3
  const int l = lane & 15;        // lane within group; owns dims 8l..8l+7
  const f32x4* q4  = reinterpret_cast<const f32x4*>(q)  + (size_t)wid * 32;
  const f32x4* qw4 = reinterpret_cast<const f32x4*>(qw) + (size_t)wid * 32;
  const f32x4* be4 = reinterpret_cast<const f32x4*>(be);
  const f32x4 qv0 = q4[2 * l],  qv1 = q4[2 * l + 1];
  const f32x4 qwv0 = qw4[2 * l], qwv1 = qw4[2 * l + 1];
  float qbe = dotv(qv0, be4[2 * l]) + dotv(qv1, be4[2 * l + 1]);
#pragma unroll
  for (int d = 1; d < 16; d <<= 1) qbe += __shfl_xor(qbe, d, 64);

  const f32x4* kv4 = reinterpret_cast<const f32x4*>(kv);
  const f32x4* ea4 = reinterpret_cast<const f32x4*>(ea);
  float denom = 0.f;
  f32x4 av0 = (f32x4)(0.f), av1 = (f32x4)(0.f), ag0 = (f32x4)(0.f), ag1 = (f32x4)(0.f);
  const int e0 = offs[wid], e1 = offs[wid + 1];
  for (int base = e0 + 4 * g; base < e1; base += 16) {
    const int rem = e1 - base;   // >= 1
    long long pk[4];
#pragma unroll
    for (int j = 0; j < 4; ++j)
      pk[j] = ntloadll(srt + base + ((j < rem) ? j : 0));
    f32x4 K0[4], K1[4], V0[4], V1[4], F0[4], F1[4];
#pragma unroll
    for (int j = 0; j < 4; ++j) {
      const int e = (int)pk[j];
      const int s = (int)(pk[j] >> 32);
      const f32x4* kvp = kv4 + (size_t)s * 64 + 2 * l;
      K0[j] = kvp[0]; K1[j] = kvp[1]; V0[j] = kvp[32]; V1[j] = kvp[33];
      const f32x4* eap = ea4 + (size_t)e * 32 + 2 * l;
      F0[j] = ntload4(eap); F1[j] = ntload4(eap + 1);
    }
    float pj[4];
#pragma unroll
    for (int j = 0; j < 4; ++j)
      pj[j] = dotv(qv0, K0[j]) + dotv(qv1, K1[j]) + dotv(qwv0, F0[j]) + dotv(qwv1, F1[j]);
#pragma unroll
    for (int d = 1; d < 16; d <<= 1) {
#pragma unroll
      for (int j = 0; j < 4; ++j) pj[j] += __shfl_xor(pj[j], d, 64);
    }
#pragma unroll
    for (int j = 0; j < 4; ++j) {
      const float wj = (j < rem) ? __expf((pj[j] + qbe) * 0.08838834764831845f) : 0.f;
      denom += wj;
      av0 += wj * V0[j]; av1 += wj * V1[j];
      ag0 += wj * F0[j]; ag1 += wj * F1[j];
    }
  }
  // cross-group combine (xor 16, 32)
#pragma unroll
  for (int d = 16; d < 64; d <<= 1) {
    denom += __shfl_xor(denom, d, 64);
#pragma unroll
    for (int c = 0; c < 4; ++c) {
      av0[c] += __shfl_xor(av0[c], d, 64);
      av1[c] += __shfl_xor(av1[c], d, 64);
      ag0[c] += __shfl_xor(ag0[c], d, 64);
      ag1[c] += __shfl_xor(ag1[c], d, 64);
    }
  }
  if (g == 0) {
    const float inv = 1.f / (denom + 1e-16f);
    f32x4* aggv4 = reinterpret_cast<f32x4*>(aggv) + (size_t)wid * 32;
    f32x4* agge4 = reinterpret_cast<f32x4*>(agge) + (size_t)wid * 32;
    aggv4[2 * l]     = av0 * inv;
    aggv4[2 * l + 1] = av1 * inv;
    agge4[2 * l]     = ag0 * inv;
    agge4[2 * l + 1] = ag1 * inv;
  }
}

// -------- per-graph top-k via bitonic sort (desc, tie -> lower index); writes nmap --------
__global__ __launch_bounds__(1024) void topk_kernel(
    const float* __restrict__ score, int* __restrict__ perm,
    float* __restrict__ tops, float* __restrict__ batchf, int* __restrict__ nmap) {
  __shared__ float ss[1024];
  __shared__ int si[1024];
  const int b = blockIdx.x, t = threadIdx.x;
  ss[t] = score[b * 1024 + t];
  si[t] = t;
  __syncthreads();
  for (int size = 2; size <= 1024; size <<= 1) {
    for (int stride = size >> 1; stride > 0; stride >>= 1) {
      const int j = t ^ stride;
      if (j > t) {
        const float s1 = ss[t], s2 = ss[j];
        const int i1 = si[t], i2 = si[j];
        const bool bj = (s2 > s1) || (s2 == s1 && i2 < i1);
        const bool dir = ((t & size) == 0);
        if (dir ? bj : !bj) { ss[t] = s2; ss[j] = s1; si[t] = i2; si[j] = i1; }
      }
      __syncthreads();
    }
  }
  if (t < TOPK) {
    const int g = b * TOPK + t;
    perm[g] = b * 1024 + si[t];
    tops[g] = ss[t];
    batchf[g] = (float)b;
    nmap[b * 1024 + si[t]] = g;
  }
}

// ------------- gather xp = out[perm]*top_s + BN partial sums -------------
__global__ __launch_bounds__(128) void xp_kernel(
    const float* __restrict__ outc, const int* __restrict__ perm,
    const float* __restrict__ tops, float* __restrict__ y,
    float* __restrict__ bnsum, float* __restrict__ bnsq) {
  const int t = threadIdx.x;
  const int r0 = blockIdx.x * 128;
  float s = 0.f, s2 = 0.f;
  for (int i = 0; i < 128; ++i) {
    const int r = r0 + i;
    const int g = perm[r];
    const float val = outc[(size_t)g * DIM + t] * tops[r];
    y[(size_t)r * DIM + t] = val;
    s += val;
    s2 = fmaf(val, val, s2);
  }
  atomicAdd(&bnsum[t], s);
  atomicAdd(&bnsq[t], s2);
}

// BN finalize folded into apply: each thread derives a/c for its 4 columns
__global__ __launch_bounds__(256) void bnapply_v2(
    float* __restrict__ y, const float* __restrict__ bnsum, const float* __restrict__ bnsq,
    const float* __restrict__ gamma, const float* __restrict__ beta) {
  const size_t i4 = (size_t)blockIdx.x * 256 + threadIdx.x;   // BKR*32 float4s
  const int c4 = (int)(i4 & 31);
  f32x4 a, c;
#pragma unroll
  for (int j = 0; j < 4; ++j) {
    const int col = c4 * 4 + j;
    const float mu = bnsum[col] * (1.f / BKR);
    const float var = bnsq[col] * (1.f / BKR) - mu * mu;
    const float aa = gamma[col] * rsqrtf(var + 1e-5f);
    a[j] = aa;
    c[j] = beta[col] - mu * aa;
  }
  f32x4 v = reinterpret_cast<f32x4*>(y)[i4];
#pragma unroll
  for (int j = 0; j < 4; ++j) v[j] = fmaf(v[j], a[j], c[j]);
  reinterpret_cast<f32x4*>(y)[i4] = v;
}

// ---------------- fused edge remap + valid + masked edge_attr ----------------
__global__ __launch_bounds__(256) void efnea_kernel(
    const int* __restrict__ srcArr, const int* __restrict__ dstArr,
    const int* __restrict__ nm, const float* __restrict__ ea,
    float* __restrict__ nei, float* __restrict__ validf, float* __restrict__ nea) {
  const int row = blockIdx.x * 8 + (threadIdx.x >> 5);
  const int lane = threadIdx.x & 31;
  const int ns = nm[srcArr[row]];
  const int nd = nm[dstArr[row]];
  const bool val = (ns >= 0) && (nd >= 0);
  if (lane == 0) {
    nei[row] = val ? (float)ns : -1.f;
    nei[NEDGE + row] = val ? (float)nd : -1.f;
    validf[row] = val ? 1.f : 0.f;
  }
  const size_t i4 = (size_t)row * 32 + lane;
  f32x4 v = (f32x4)(0.f);
  if (val) v = ntload4(reinterpret_cast<const f32x4*>(ea) + i4);
  ntstore4(reinterpret_cast<f32x4*>(nea) + i4, v);
}

// ---------------- launch ----------------
extern "C" void kernel_launch(void* const* d_in, const int* in_sizes, int n_in,
                              void* d_out, int out_size, void* d_ws, size_t ws_size,
                              hipStream_t stream) {
  const float* x     = (const float*)d_in[0];
  const int*   eidx  = (const int*)d_in[1];
  const float* eattr = (const float*)d_in[2];
  const float* Wq = (const float*)d_in[4];  const float* bq = (const float*)d_in[5];
  const float* Wk = (const float*)d_in[6];  const float* bk = (const float*)d_in[7];
  const float* Wv = (const float*)d_in[8];  const float* bv = (const float*)d_in[9];
  const float* We = (const float*)d_in[10]; const float* be = (const float*)d_in[11];
  const float* Ws = (const float*)d_in[12]; const float* bs = (const float*)d_in[13];
  const float* pool_w = (const float*)d_in[14];
  const float* gamma  = (const float*)d_in[15];
  const float* beta   = (const float*)d_in[16];

  const int* srcArr = eidx;
  const int* dstArr = eidx + NEDGE;

  float* out = (float*)d_out;
  // output layout (floats)
  float* y      = out;                                   // BKR*128
  float* nei    = out + (size_t)BKR * DIM;               // 2*NEDGE
  float* nea    = nei + 2 * (size_t)NEDGE;               // NEDGE*128
  float* batchf = nea + (size_t)NEDGE * DIM;             // BKR
  float* validf = batchf + BKR;                          // NEDGE

  // big node arrays staged inside the (not-yet-written) nea region: 8 x NM = 256MB
  float* q    = nea + 0 * NM;
  float* kv   = nea + 1 * NM;   // 2*NM (k|v interleaved, 256 floats/row)
  float* sl   = nea + 3 * NM;
  float* qw   = nea + 4 * NM;
  float* aggv = nea + 5 * NM;
  float* agge = nea + 6 * NM;
  float* outc = nea + 7 * NM;

  // workspace layout (small)
  char* w = (char*)d_ws;
  size_t off = 0;
  float* score= (float*)(w + off); off += (size_t)NODES * 4;
  float* pwn  = (float*)(w + off); off += 128 * 4;
  float* Wc   = (float*)(w + off); off += 128 * 128 * 4;
  float* bc   = (float*)(w + off); off += 128 * 4;
  float* tops = (float*)(w + off); off += (size_t)BKR * 4;
  float* bnsum= (float*)(w + off); off += 128 * 4;
  float* bnsq = (float*)(w + off); off += 128 * 4;
  int* deg    = (int*)(w + off); off += (size_t)NODES * 4;
  int* offs   = (int*)(w + off); off += ((size_t)NODES + 8) * 4;
  int* woff   = (int*)(w + off); off += (size_t)NODES * 4;
  int* nmap   = (int*)(w + off); off += (size_t)NODES * 4;
  int* perm   = (int*)(w + off); off += (size_t)BKR * 4;
  long long* srt = (long long*)(w + off); off += (size_t)NEDGE * 8;

  // fused setup: init + pwn + Wc  (blocks: 256 init | 1 pwn | 64 Wc)
  setup_kernel<<<321, 256, 0, stream>>>(pool_w, pwn, Wq, bq, We, Wc, bc,
                                        deg, nmap, (float*)bnsum);

  // node-level linear layers (q, k|v, skip, qW) in one launch
  gemm_multi<<<5 * 256, 512, 0, stream>>>(
      x, Wq, bq, q, Wk, bk, Wv, bv, kv, Ws, bs, sl, Wc, bc, qw);

  // CSR by dst
  deg_kernel<<<NEDGE / 256, 256, 0, stream>>>(dstArr, deg);
  scan_kernel<<<1, 1024, 0, stream>>>(deg, offs, woff);
  scatter_kernel<<<NEDGE / 256, 256, 0, stream>>>(dstArr, srcArr, woff, srt);

  // fused attention on raw edge_attr (NT stream), 16 edges in flight per wave
  attn_v5<<<NODES / 4, 256, 0, stream>>>(q, kv, qw, eattr, be, srt, offs, aggv, agge);

  // final conv output + score
  gemm_final<<<NODES / 128, 256, 0, stream>>>(agge, We, be, aggv, sl, pwn, outc, score);

  // top-k pooling (writes perm/tops/batch + nmap)
  topk_kernel<<<NB, 1024, 0, stream>>>(score, perm, tops, batchf, nmap);

  // xp gather + BN (must finish with outc before nea overwrite)
  xp_kernel<<<BKR / 128, 128, 0, stream>>>(outc, perm, tops, y, bnsum, bnsq);
  bnapply_v2<<<(BKR * 32) / 256, 256, 0, stream>>>(y, bnsum, bnsq, gamma, beta);

  // fused edge remap + masked edge_attr (overwrites staging region last)
  efnea_kernel<<<NEDGE / 8, 256, 0, stream>>>(srcArr, dstArr, nmap, eattr, nei, validf, nea);
}

// Round 7
// 731.222 us; speedup vs baseline: 1.0243x; 1.0243x over previous
//
#include <hip/hip_runtime.h>
#include <cstddef>
#include <cstdint>

#define NODES 65536      // B*N
#define NEDGE 1048576    // B*E_PER
#define NB    64
#define NPER  1024
#define TOPK  512
#define BKR   32768      // NB*TOPK
#define DIM   128
#define NM    ((size_t)NODES * DIM)   // floats per node-array

typedef float f32x4 __attribute__((ext_vector_type(4)));

__device__ __forceinline__ f32x4 ntload4(const f32x4* p) {
  return __builtin_nontemporal_load(p);
}
__device__ __forceinline__ void ntstore4(f32x4* p, f32x4 v) {
  __builtin_nontemporal_store(v, p);
}
__device__ __forceinline__ long long ntloadll(const long long* p) {
  return __builtin_nontemporal_load(p);
}
__device__ __forceinline__ float dotv(f32x4 a, f32x4 b) {
  return fmaf(a.x, b.x, fmaf(a.y, b.y, fmaf(a.z, b.z, a.w * b.w)));
}

// ================= shared GEMM core: Out[row0..row0+7] = A-rows @ sW + bias =============
__device__ __forceinline__ void gemm_core(
    const float* __restrict__ A, const f32x4* __restrict__ sW,
    const float* __restrict__ bias, float* __restrict__ Out,
    size_t row0, int ostride, int tc) {
  const float* a0 = A + row0 * 128;
  f32x4 acc0[8], acc1[8];
#pragma unroll
  for (int r = 0; r < 8; ++r) { acc0[r] = (f32x4)(0.f); acc1[r] = (f32x4)(0.f); }
#pragma unroll 4
  for (int k4 = 0; k4 < 32; ++k4) {
    f32x4 a[8];
#pragma unroll
    for (int r = 0; r < 8; ++r)
      a[r] = *reinterpret_cast<const f32x4*>(a0 + r * 128 + k4 * 4);
#pragma unroll
    for (int kk = 0; kk < 4; ++kk) {
      const f32x4 w0 = sW[(k4 * 4 + kk) * 32 + tc * 2];
      const f32x4 w1 = sW[(k4 * 4 + kk) * 32 + tc * 2 + 1];
#pragma unroll
      for (int r = 0; r < 8; ++r) {
        const float av = a[r][kk];
        acc0[r] += av * w0;
        acc1[r] += av * w1;
      }
    }
  }
  const f32x4 b0 = reinterpret_cast<const f32x4*>(bias)[tc * 2];
  const f32x4 b1 = reinterpret_cast<const f32x4*>(bias)[tc * 2 + 1];
#pragma unroll
  for (int r = 0; r < 8; ++r) {
    f32x4* outp = reinterpret_cast<f32x4*>(Out + (row0 + r) * (size_t)ostride + tc * 8);
    outp[0] = acc0[r] + b0;
    outp[1] = acc1[r] + b1;
  }
}

// 4 GEMMs in one launch, 512 threads, 256 rows/block; k,v interleaved into kv[*][256]
__global__ __launch_bounds__(512) void gemm_multi(
    const float* __restrict__ x,
    const float* __restrict__ Wq, const float* __restrict__ bq, float* __restrict__ q,
    const float* __restrict__ Wk, const float* __restrict__ bk,
    const float* __restrict__ Wv, const float* __restrict__ bv, float* __restrict__ kv,
    const float* __restrict__ Wc, const float* __restrict__ bc, float* __restrict__ qw) {
  __shared__ f32x4 sW[128 * 32];
  const int which = blockIdx.x >> 8;
  const int bid = blockIdx.x & 255;
  const int t = threadIdx.x;
  const float* W; const float* bias; float* Out; int ostride = 128;
  if (which == 0)      { W = Wq; bias = bq; Out = q; }
  else if (which == 1) { W = Wk; bias = bk; Out = kv;       ostride = 256; }
  else if (which == 2) { W = Wv; bias = bv; Out = kv + 128; ostride = 256; }
  else                 { W = Wc; bias = bc; Out = qw; }
  const f32x4* W4 = reinterpret_cast<const f32x4*>(W);
#pragma unroll
  for (int i = 0; i < 8; ++i) sW[t + i * 512] = W4[t + i * 512];
  __syncthreads();
  gemm_core(x, sW, bias, Out, (size_t)bid * 256 + (t >> 4) * 8, ostride, t & 15);
}

// ====== final: outc = relu(agge@We + x@Ws + be + bs + aggv); score epilogue ======
// Concatenated-K GEMM: phase 1 uses We in LDS on agge, phase 2 reloads LDS with Ws on x.
__global__ __launch_bounds__(256) void gemm_final2(
    const float* __restrict__ agge, const float* __restrict__ We,
    const float* __restrict__ x,    const float* __restrict__ Ws,
    const float* __restrict__ be,   const float* __restrict__ bs,
    const float* __restrict__ aggv, const float* __restrict__ pwn,
    float* __restrict__ outc, float* __restrict__ score) {
  __shared__ f32x4 sW[128 * 32];
  const int t = threadIdx.x;
  const int tc = t & 15;
  const size_t row0 = (size_t)blockIdx.x * 128 + (t >> 4) * 8;
  f32x4 acc0[8], acc1[8];
#pragma unroll
  for (int r = 0; r < 8; ++r) { acc0[r] = (f32x4)(0.f); acc1[r] = (f32x4)(0.f); }

#pragma unroll
  for (int phase = 0; phase < 2; ++phase) {
    const float* W = phase ? Ws : We;
    const float* A = phase ? x : agge;
    const f32x4* W4 = reinterpret_cast<const f32x4*>(W);
    if (phase) __syncthreads();          // all waves done reading previous sW
#pragma unroll
    for (int i = 0; i < 16; ++i) sW[t + i * 256] = W4[t + i * 256];
    __syncthreads();
    const float* a0 = A + row0 * 128;
#pragma unroll 4
    for (int k4 = 0; k4 < 32; ++k4) {
      f32x4 a[8];
#pragma unroll
      for (int r = 0; r < 8; ++r)
        a[r] = *reinterpret_cast<const f32x4*>(a0 + r * 128 + k4 * 4);
#pragma unroll
      for (int kk = 0; kk < 4; ++kk) {
        const f32x4 w0 = sW[(k4 * 4 + kk) * 32 + tc * 2];
        const f32x4 w1 = sW[(k4 * 4 + kk) * 32 + tc * 2 + 1];
#pragma unroll
        for (int r = 0; r < 8; ++r) {
          const float av = a[r][kk];
          acc0[r] += av * w0;
          acc1[r] += av * w1;
        }
      }
    }
  }
  const f32x4 b0 = reinterpret_cast<const f32x4*>(be)[tc * 2] +
                   reinterpret_cast<const f32x4*>(bs)[tc * 2];
  const f32x4 b1 = reinterpret_cast<const f32x4*>(be)[tc * 2 + 1] +
                   reinterpret_cast<const f32x4*>(bs)[tc * 2 + 1];
  const f32x4 p0 = reinterpret_cast<const f32x4*>(pwn)[tc * 2];
  const f32x4 p1 = reinterpret_cast<const f32x4*>(pwn)[tc * 2 + 1];
#pragma unroll
  for (int r = 0; r < 8; ++r) {
    const f32x4 v0 = reinterpret_cast<const f32x4*>(aggv + (row0 + r) * 128 + tc * 8)[0];
    const f32x4 v1 = reinterpret_cast<const f32x4*>(aggv + (row0 + r) * 128 + tc * 8)[1];
    f32x4 o0 = acc0[r] + b0 + v0;
    f32x4 o1 = acc1[r] + b1 + v1;
#pragma unroll
    for (int c = 0; c < 4; ++c) { o0[c] = fmaxf(o0[c], 0.f); o1[c] = fmaxf(o1[c], 0.f); }
    f32x4* outp = reinterpret_cast<f32x4*>(outc + (row0 + r) * 128 + tc * 8);
    outp[0] = o0; outp[1] = o1;
    float sp = dotv(o0, p0) + dotv(o1, p1);
#pragma unroll
    for (int d = 1; d < 16; d <<= 1) sp += __shfl_xor(sp, d, 16);
    if (tc == 0) score[row0 + r] = tanhf(sp);
  }
}

// ===== fused setup: init deg/nmap/bn2 + pwn + Wc[t,i]=sum_d Wq[t,d]*We[i,d] =====
__global__ __launch_bounds__(256) void setup_kernel(
    const float* __restrict__ pool_w, float* __restrict__ pwn,
    const float* __restrict__ Wq, const float* __restrict__ bq,
    const float* __restrict__ We, float* __restrict__ Wc, float* __restrict__ bc,
    int* __restrict__ deg, int* __restrict__ nmap, float* __restrict__ bn2) {
  const int blk = blockIdx.x;
  const int t = threadIdx.x;
  if (blk < 256) {                 // init
    const int i = blk * 256 + t;
    deg[i] = 0; nmap[i] = -1;
    if (i < 256) bn2[i] = 0.f;     // bnsum[128]+bnsq[128]
  } else if (blk == 256) {         // pool_w normalization
    __shared__ float red[128];
    if (t < 128) {
      const float vv = pool_w[t];
      red[t] = vv * vv;
    }
    __syncthreads();
    for (int d = 64; d > 0; d >>= 1) {
      if (t < d) red[t] += red[t + d];
      __syncthreads();
    }
    if (t < 128) pwn[t] = pool_w[t] * rsqrtf(red[0]);
  } else {                         // Wc: 2 output cols per block
    __shared__ float sWe[2][128];
    const int i = (blk - 257) * 2 + (t >> 7);   // output col
    const int tl = t & 127;
    sWe[t >> 7][tl] = We[i * 128 + tl];
    __syncthreads();
    float s = 0.f;
    for (int d = 0; d < 128; ++d) s = fmaf(Wq[tl * 128 + d], sWe[t >> 7][d], s);
    Wc[tl * 128 + i] = s;
    if (tl == 0) {
      float sb = 0.f;
      for (int d = 0; d < 128; ++d) sb = fmaf(bq[d], sWe[t >> 7][d], sb);
      bc[i] = sb;
    }
  }
}

// ---------------- CSR build ----------------
__global__ void deg_kernel(const int* __restrict__ dst, int* __restrict__ deg) {
  const int e = blockIdx.x * 256 + threadIdx.x;
  atomicAdd(&deg[dst[e]], 1);
}

__global__ __launch_bounds__(1024) void scan_kernel(const int* __restrict__ deg,
                                                    int* __restrict__ offs,
                                                    int* __restrict__ woff) {
  __shared__ int part[1024];
  const int t = threadIdx.x;
  const int base = t * 64;
  int s = 0;
  for (int j = 0; j < 64; ++j) s += deg[base + j];
  part[t] = s;
  __syncthreads();
  for (int d = 1; d < 1024; d <<= 1) {
    const int add = (t >= d) ? part[t - d] : 0;
    __syncthreads();
    part[t] += add;
    __syncthreads();
  }
  int run = part[t] - s;
  for (int j = 0; j < 64; ++j) {
    offs[base + j] = run; woff[base + j] = run;
    run += deg[base + j];
  }
  if (t == 1023) offs[NODES] = run;
}

// sorted edge array: packed (src<<32 | e)
__global__ void scatter_kernel(const int* __restrict__ dst, const int* __restrict__ src,
                               int* __restrict__ woff, long long* __restrict__ srt) {
  const int e = blockIdx.x * 256 + threadIdx.x;
  const int pos = atomicAdd(&woff[dst[e]], 1);
  srt[pos] = ((long long)src[e] << 32) | (unsigned)e;
}

// ========== fused attention: 4x16-lane groups per wave, 2 edges/group in flight ==========
// kv interleaved [node][256]; ea read with NONTEMPORAL loads (keep kv/q/qw L2-resident)
__global__ __launch_bounds__(256) void attn_v6(
    const float* __restrict__ q, const float* __restrict__ kv,
    const float* __restrict__ qw, const float* __restrict__ ea,
    const float* __restrict__ be, const long long* __restrict__ srt,
    const int* __restrict__ offs, float* __restrict__ aggv,
    float* __restrict__ agge) {
  int b = blockIdx.x;
  b = (b & 7) * 2048 + (b >> 3);                        // XCD-bijective swizzle (16384%8==0)
  const int wid = b * 4 + (threadIdx.x >> 6);
  const int lane = threadIdx.x & 63;
  const int g = lane >> 4;        // edge-group 0..3
  const int l = lane & 15;        // lane within group; owns dims 8l..8l+7
  const f32x4* q4  = reinterpret_cast<const f32x4*>(q)  + (size_t)wid * 32;
  const f32x4* qw4 = reinterpret_cast<const f32x4*>(qw) + (size_t)wid * 32;
  const f32x4* be4 = reinterpret_cast<const f32x4*>(be);
  const f32x4 qv0 = q4[2 * l],  qv1 = q4[2 * l + 1];
  const f32x4 qwv0 = qw4[2 * l], qwv1 = qw4[2 * l + 1];
  float qbe = dotv(qv0, be4[2 * l]) + dotv(qv1, be4[2 * l + 1]);
#pragma unroll
  for (int d = 1; d < 16; d <<= 1) qbe += __shfl_xor(qbe, d, 64);

  const f32x4* kv4 = reinterpret_cast<const f32x4*>(kv);
  const f32x4* ea4 = reinterpret_cast<const f32x4*>(ea);
  float denom = 0.f;
  f32x4 av0 = (f32x4)(0.f), av1 = (f32x4)(0.f), ag0 = (f32x4)(0.f), ag1 = (f32x4)(0.f);
  const int e0 = offs[wid], e1 = offs[wid + 1];
  for (int p = e0 + g; p < e1; p += 8) {
    const bool h2 = (p + 4) < e1;
    const long long pkA = ntloadll(srt + p);
    const long long pkB = h2 ? ntloadll(srt + p + 4) : pkA;
    const int eA = (int)pkA, sA = (int)(pkA >> 32);
    const int eB = (int)pkB, sB = (int)(pkB >> 32);
    const f32x4* kvA = kv4 + (size_t)sA * 64 + 2 * l;
    const f32x4* kvB = kv4 + (size_t)sB * 64 + 2 * l;
    const f32x4 kA0 = kvA[0], kA1 = kvA[1], vA0 = kvA[32], vA1 = kvA[33];
    const f32x4 kB0 = kvB[0], kB1 = kvB[1], vB0 = kvB[32], vB1 = kvB[33];
    const f32x4 fA0 = ntload4(ea4 + (size_t)eA * 32 + 2 * l);
    const f32x4 fA1 = ntload4(ea4 + (size_t)eA * 32 + 2 * l + 1);
    const f32x4 fB0 = ntload4(ea4 + (size_t)eB * 32 + 2 * l);
    const f32x4 fB1 = ntload4(ea4 + (size_t)eB * 32 + 2 * l + 1);
    float pA = dotv(qv0, kA0) + dotv(qv1, kA1) + dotv(qwv0, fA0) + dotv(qwv1, fA1);
    float pB = dotv(qv0, kB0) + dotv(qv1, kB1) + dotv(qwv0, fB0) + dotv(qwv1, fB1);
#pragma unroll
    for (int d = 1; d < 16; d <<= 1) {
      pA += __shfl_xor(pA, d, 64);
      pB += __shfl_xor(pB, d, 64);
    }
    const float wA = __expf((pA + qbe) * 0.08838834764831845f);   // /sqrt(128)
    const float wB = h2 ? __expf((pB + qbe) * 0.08838834764831845f) : 0.f;
    denom += wA + wB;
    av0 += wA * vA0 + wB * vB0;
    av1 += wA * vA1 + wB * vB1;
    ag0 += wA * fA0 + wB * fB0;
    ag1 += wA * fA1 + wB * fB1;
  }
  // cross-group combine (xor 16, 32)
#pragma unroll
  for (int d = 16; d < 64; d <<= 1) {
    denom += __shfl_xor(denom, d, 64);
#pragma unroll
    for (int c = 0; c < 4; ++c) {
      av0[c] += __shfl_xor(av0[c], d, 64);
      av1[c] += __shfl_xor(av1[c], d, 64);
      ag0[c] += __shfl_xor(ag0[c], d, 64);
      ag1[c] += __shfl_xor(ag1[c], d, 64);
    }
  }
  if (g == 0) {
    const float inv = 1.f / (denom + 1e-16f);
    f32x4* aggv4 = reinterpret_cast<f32x4*>(aggv) + (size_t)wid * 32;
    f32x4* agge4 = reinterpret_cast<f32x4*>(agge) + (size_t)wid * 32;
    aggv4[2 * l]     = av0 * inv;
    aggv4[2 * l + 1] = av1 * inv;
    agge4[2 * l]     = ag0 * inv;
    agge4[2 * l + 1] = ag1 * inv;
  }
}

// -------- per-graph top-k via bitonic sort (desc, tie -> lower index); writes nmap --------
__global__ __launch_bounds__(1024) void topk_kernel(
    const float* __restrict__ score, int* __restrict__ perm,
    float* __restrict__ tops, float* __restrict__ batchf, int* __restrict__ nmap) {
  __shared__ float ss[1024];
  __shared__ int si[1024];
  const int b = blockIdx.x, t = threadIdx.x;
  ss[t] = score[b * 1024 + t];
  si[t] = t;
  __syncthreads();
  for (int size = 2; size <= 1024; size <<= 1) {
    for (int stride = size >> 1; stride > 0; stride >>= 1) {
      const int j = t ^ stride;
      if (j > t) {
        const float s1 = ss[t], s2 = ss[j];
        const int i1 = si[t], i2 = si[j];
        const bool bj = (s2 > s1) || (s2 == s1 && i2 < i1);
        const bool dir = ((t & size) == 0);
        if (dir ? bj : !bj) { ss[t] = s2; ss[j] = s1; si[t] = i2; si[j] = i1; }
      }
      __syncthreads();
    }
  }
  if (t < TOPK) {
    const int g = b * TOPK + t;
    perm[g] = b * 1024 + si[t];
    tops[g] = ss[t];
    batchf[g] = (float)b;
    nmap[b * 1024 + si[t]] = g;
  }
}

// ------------- gather xp = out[perm]*top_s + BN partial sums -------------
__global__ __launch_bounds__(128) void xp_kernel(
    const float* __restrict__ outc, const int* __restrict__ perm,
    const float* __restrict__ tops, float* __restrict__ y,
    float* __restrict__ bnsum, float* __restrict__ bnsq) {
  const int t = threadIdx.x;
  const int r0 = blockIdx.x * 128;
  float s = 0.f, s2 = 0.f;
  for (int i = 0; i < 128; ++i) {
    const int r = r0 + i;
    const int g = perm[r];
    const float val = outc[(size_t)g * DIM + t] * tops[r];
    y[(size_t)r * DIM + t] = val;
    s += val;
    s2 = fmaf(val, val, s2);
  }
  atomicAdd(&bnsum[t], s);
  atomicAdd(&bnsq[t], s2);
}

// BN finalize folded into apply: each thread derives a/c for its 4 columns
__global__ __launch_bounds__(256) void bnapply_v2(
    float* __restrict__ y, const float* __restrict__ bnsum, const float* __restrict__ bnsq,
    const float* __restrict__ gamma, const float* __restrict__ beta) {
  const size_t i4 = (size_t)blockIdx.x * 256 + threadIdx.x;   // BKR*32 float4s
  const int c4 = (int)(i4 & 31);
  f32x4 a, c;
#pragma unroll
  for (int j = 0; j < 4; ++j) {
    const int col = c4 * 4 + j;
    const float mu = bnsum[col] * (1.f / BKR);
    const float var = bnsq[col] * (1.f / BKR) - mu * mu;
    const float aa = gamma[col] * rsqrtf(var + 1e-5f);
    a[j] = aa;
    c[j] = beta[col] - mu * aa;
  }
  f32x4 v = reinterpret_cast<f32x4*>(y)[i4];
#pragma unroll
  for (int j = 0; j < 4; ++j) v[j] = fmaf(v[j], a[j], c[j]);
  reinterpret_cast<f32x4*>(y)[i4] = v;
}

// ---------------- fused edge remap + valid + masked edge_attr ----------------
__global__ __launch_bounds__(256) void efnea_kernel(
    const int* __restrict__ srcArr, const int* __restrict__ dstArr,
    const int* __restrict__ nm, const float* __restrict__ ea,
    float* __restrict__ nei, float* __restrict__ validf, float* __restrict__ nea) {
  const int row = blockIdx.x * 8 + (threadIdx.x >> 5);
  const int lane = threadIdx.x & 31;
  const int ns = nm[srcArr[row]];
  const int nd = nm[dstArr[row]];
  const bool val = (ns >= 0) && (nd >= 0);
  if (lane == 0) {
    nei[row] = val ? (float)ns : -1.f;
    nei[NEDGE + row] = val ? (float)nd : -1.f;
    validf[row] = val ? 1.f : 0.f;
  }
  const size_t i4 = (size_t)row * 32 + lane;
  f32x4 v = (f32x4)(0.f);
  if (val) v = ntload4(reinterpret_cast<const f32x4*>(ea) + i4);
  ntstore4(reinterpret_cast<f32x4*>(nea) + i4, v);
}

// ---------------- launch ----------------
extern "C" void kernel_launch(void* const* d_in, const int* in_sizes, int n_in,
                              void* d_out, int out_size, void* d_ws, size_t ws_size,
                              hipStream_t stream) {
  const float* x     = (const float*)d_in[0];
  const int*   eidx  = (const int*)d_in[1];
  const float* eattr = (const float*)d_in[2];
  const float* Wq = (const float*)d_in[4];  const float* bq = (const float*)d_in[5];
  const float* Wk = (const float*)d_in[6];  const float* bk = (const float*)d_in[7];
  const float* Wv = (const float*)d_in[8];  const float* bv = (const float*)d_in[9];
  const float* We = (const float*)d_in[10]; const float* be = (const float*)d_in[11];
  const float* Ws = (const float*)d_in[12]; const float* bs = (const float*)d_in[13];
  const float* pool_w = (const float*)d_in[14];
  const float* gamma  = (const float*)d_in[15];
  const float* beta   = (const float*)d_in[16];

  const int* srcArr = eidx;
  const int* dstArr = eidx + NEDGE;

  float* out = (float*)d_out;
  // output layout (floats)
  float* y      = out;                                   // BKR*128
  float* nei    = out + (size_t)BKR * DIM;               // 2*NEDGE
  float* nea    = nei + 2 * (size_t)NEDGE;               // NEDGE*128
  float* batchf = nea + (size_t)NEDGE * DIM;             // BKR
  float* validf = batchf + BKR;                          // NEDGE

  // big node arrays staged inside the (not-yet-written) nea region: 7 x NM = 224MB
  float* q    = nea + 0 * NM;
  float* kv   = nea + 1 * NM;   // 2*NM (k|v interleaved, 256 floats/row)
  float* qw   = nea + 3 * NM;
  float* aggv = nea + 4 * NM;
  float* agge = nea + 5 * NM;
  float* outc = nea + 6 * NM;

  // workspace layout (small)
  char* w = (char*)d_ws;
  size_t off = 0;
  float* score= (float*)(w + off); off += (size_t)NODES * 4;
  float* pwn  = (float*)(w + off); off += 128 * 4;
  float* Wc   = (float*)(w + off); off += 128 * 128 * 4;
  float* bc   = (float*)(w + off); off += 128 * 4;
  float* tops = (float*)(w + off); off += (size_t)BKR * 4;
  float* bnsum= (float*)(w + off); off += 128 * 4;
  float* bnsq = (float*)(w + off); off += 128 * 4;
  int* deg    = (int*)(w + off); off += (size_t)NODES * 4;
  int* offs   = (int*)(w + off); off += ((size_t)NODES + 8) * 4;
  int* woff   = (int*)(w + off); off += (size_t)NODES * 4;
  int* nmap   = (int*)(w + off); off += (size_t)NODES * 4;
  int* perm   = (int*)(w + off); off += (size_t)BKR * 4;
  long long* srt = (long long*)(w + off); off += (size_t)NEDGE * 8;

  // fused setup: init + pwn + Wc  (blocks: 256 init | 1 pwn | 64 Wc)
  setup_kernel<<<321, 256, 0, stream>>>(pool_w, pwn, Wq, bq, We, Wc, bc,
                                        deg, nmap, (float*)bnsum);

  // node-level linear layers (q, k|v, qW) in one launch
  gemm_multi<<<4 * 256, 512, 0, stream>>>(
      x, Wq, bq, q, Wk, bk, Wv, bv, kv, Wc, bc, qw);

  // CSR by dst
  deg_kernel<<<NEDGE / 256, 256, 0, stream>>>(dstArr, deg);
  scan_kernel<<<1, 1024, 0, stream>>>(deg, offs, woff);
  scatter_kernel<<<NEDGE / 256, 256, 0, stream>>>(dstArr, srcArr, woff, srt);

  // fused attention on raw edge_attr (NT stream)
  attn_v6<<<NODES / 4, 256, 0, stream>>>(q, kv, qw, eattr, be, srt, offs, aggv, agge);

  // final conv output (+ fused skip GEMM) + score
  gemm_final2<<<NODES / 128, 256, 0, stream>>>(agge, We, x, Ws, be, bs, aggv, pwn,
                                               outc, score);

  // top-k pooling (writes perm/tops/batch + nmap)
  topk_kernel<<<NB, 1024, 0, stream>>>(score, perm, tops, batchf, nmap);

  // xp gather + BN (must finish with outc before nea overwrite)
  xp_kernel<<<BKR / 128, 128, 0, stream>>>(outc, perm, tops, y, bnsum, bnsq);
  bnapply_v2<<<(BKR * 32) / 256, 256, 0, stream>>>(y, bnsum, bnsq, gamma, beta);

  // fused edge remap + masked edge_attr (overwrites staging region last)
  efnea_kernel<<<NEDGE / 8, 256, 0, stream>>>(srcArr, dstArr, nmap, eattr, nei, validf, nea);
}

// Round 8
// 724.660 us; speedup vs baseline: 1.0336x; 1.0091x over previous
//
#include <hip/hip_runtime.h>
#include <cstddef>
#include <cstdint>

#define NODES 65536      // B*N
#define NEDGE 1048576    // B*E_PER
#define NB    64
#define NPER  1024
#define TOPK  512
#define BKR   32768      // NB*TOPK
#define DIM   128
#define NM    ((size_t)NODES * DIM)   // floats per node-array

typedef float f32x4 __attribute__((ext_vector_type(4)));

__device__ __forceinline__ f32x4 ntload4(const f32x4* p) {
  return __builtin_nontemporal_load(p);
}
__device__ __forceinline__ void ntstore4(f32x4* p, f32x4 v) {
  __builtin_nontemporal_store(v, p);
}
__device__ __forceinline__ long long ntloadll(const long long* p) {
  return __builtin_nontemporal_load(p);
}
__device__ __forceinline__ float dotv(f32x4 a, f32x4 b) {
  return fmaf(a.x, b.x, fmaf(a.y, b.y, fmaf(a.z, b.z, a.w * b.w)));
}

// ---- DPP 16-lane sum (VALU-speed, stays within one DPP row == one 16-lane group) ----
template <int CTRL>
__device__ __forceinline__ float dpp_addf(float x) {
  const int y = __builtin_amdgcn_update_dpp(0, __float_as_int(x), CTRL, 0xF, 0xF, true);
  return x + __int_as_float(y);
}
__device__ __forceinline__ float row16_sum(float x) {
  x = dpp_addf<0xB1>(x);    // quad_perm [1,0,3,2]  (xor 1)
  x = dpp_addf<0x4E>(x);    // quad_perm [2,3,0,1]  (xor 2)
  x = dpp_addf<0x124>(x);   // row_ror:4
  x = dpp_addf<0x128>(x);   // row_ror:8
  return x;
}

// ================= shared GEMM core: Out[row0..row0+7] = A-rows @ sW + bias =============
__device__ __forceinline__ void gemm_core(
    const float* __restrict__ A, const f32x4* __restrict__ sW,
    const float* __restrict__ bias, float* __restrict__ Out,
    size_t row0, int ostride, int tc) {
  const float* a0 = A + row0 * 128;
  f32x4 acc0[8], acc1[8];
#pragma unroll
  for (int r = 0; r < 8; ++r) { acc0[r] = (f32x4)(0.f); acc1[r] = (f32x4)(0.f); }
#pragma unroll 4
  for (int k4 = 0; k4 < 32; ++k4) {
    f32x4 a[8];
#pragma unroll
    for (int r = 0; r < 8; ++r)
      a[r] = *reinterpret_cast<const f32x4*>(a0 + r * 128 + k4 * 4);
#pragma unroll
    for (int kk = 0; kk < 4; ++kk) {
      const f32x4 w0 = sW[(k4 * 4 + kk) * 32 + tc * 2];
      const f32x4 w1 = sW[(k4 * 4 + kk) * 32 + tc * 2 + 1];
#pragma unroll
      for (int r = 0; r < 8; ++r) {
        const float av = a[r][kk];
        acc0[r] += av * w0;
        acc1[r] += av * w1;
      }
    }
  }
  const f32x4 b0 = reinterpret_cast<const f32x4*>(bias)[tc * 2];
  const f32x4 b1 = reinterpret_cast<const f32x4*>(bias)[tc * 2 + 1];
#pragma unroll
  for (int r = 0; r < 8; ++r) {
    f32x4* outp = reinterpret_cast<f32x4*>(Out + (row0 + r) * (size_t)ostride + tc * 8);
    outp[0] = acc0[r] + b0;
    outp[1] = acc1[r] + b1;
  }
}

// 4 GEMMs in one launch, 512 threads, 256 rows/block; k,v interleaved into kv[*][256]
__global__ __launch_bounds__(512) void gemm_multi(
    const float* __restrict__ x,
    const float* __restrict__ Wq, const float* __restrict__ bq, float* __restrict__ q,
    const float* __restrict__ Wk, const float* __restrict__ bk,
    const float* __restrict__ Wv, const float* __restrict__ bv, float* __restrict__ kv,
    const float* __restrict__ Wc, const float* __restrict__ bc, float* __restrict__ qw) {
  __shared__ f32x4 sW[128 * 32];
  const int which = blockIdx.x >> 8;
  const int bid = blockIdx.x & 255;
  const int t = threadIdx.x;
  const float* W; const float* bias; float* Out; int ostride = 128;
  if (which == 0)      { W = Wq; bias = bq; Out = q; }
  else if (which == 1) { W = Wk; bias = bk; Out = kv;       ostride = 256; }
  else if (which == 2) { W = Wv; bias = bv; Out = kv + 128; ostride = 256; }
  else                 { W = Wc; bias = bc; Out = qw; }
  const f32x4* W4 = reinterpret_cast<const f32x4*>(W);
#pragma unroll
  for (int i = 0; i < 8; ++i) sW[t + i * 512] = W4[t + i * 512];
  __syncthreads();
  gemm_core(x, sW, bias, Out, (size_t)bid * 256 + (t >> 4) * 8, ostride, t & 15);
}

// ====== final: outc = relu(agge@We + x@Ws + be + bs + aggv); score epilogue ======
// Concatenated-K GEMM: phase 1 uses We in LDS on agge, phase 2 reloads LDS with Ws on x.
__global__ __launch_bounds__(256) void gemm_final2(
    const float* __restrict__ agge, const float* __restrict__ We,
    const float* __restrict__ x,    const float* __restrict__ Ws,
    const float* __restrict__ be,   const float* __restrict__ bs,
    const float* __restrict__ aggv, const float* __restrict__ pwn,
    float* __restrict__ outc, float* __restrict__ score) {
  __shared__ f32x4 sW[128 * 32];
  const int t = threadIdx.x;
  const int tc = t & 15;
  const size_t row0 = (size_t)blockIdx.x * 128 + (t >> 4) * 8;
  f32x4 acc0[8], acc1[8];
#pragma unroll
  for (int r = 0; r < 8; ++r) { acc0[r] = (f32x4)(0.f); acc1[r] = (f32x4)(0.f); }

#pragma unroll
  for (int phase = 0; phase < 2; ++phase) {
    const float* W = phase ? Ws : We;
    const float* A = phase ? x : agge;
    const f32x4* W4 = reinterpret_cast<const f32x4*>(W);
    if (phase) __syncthreads();          // all waves done reading previous sW
#pragma unroll
    for (int i = 0; i < 16; ++i) sW[t + i * 256] = W4[t + i * 256];
    __syncthreads();
    const float* a0 = A + row0 * 128;
#pragma unroll 4
    for (int k4 = 0; k4 < 32; ++k4) {
      f32x4 a[8];
#pragma unroll
      for (int r = 0; r < 8; ++r)
        a[r] = *reinterpret_cast<const f32x4*>(a0 + r * 128 + k4 * 4);
#pragma unroll
      for (int kk = 0; kk < 4; ++kk) {
        const f32x4 w0 = sW[(k4 * 4 + kk) * 32 + tc * 2];
        const f32x4 w1 = sW[(k4 * 4 + kk) * 32 + tc * 2 + 1];
#pragma unroll
        for (int r = 0; r < 8; ++r) {
          const float av = a[r][kk];
          acc0[r] += av * w0;
          acc1[r] += av * w1;
        }
      }
    }
  }
  const f32x4 b0 = reinterpret_cast<const f32x4*>(be)[tc * 2] +
                   reinterpret_cast<const f32x4*>(bs)[tc * 2];
  const f32x4 b1 = reinterpret_cast<const f32x4*>(be)[tc * 2 + 1] +
                   reinterpret_cast<const f32x4*>(bs)[tc * 2 + 1];
  const f32x4 p0 = reinterpret_cast<const f32x4*>(pwn)[tc * 2];
  const f32x4 p1 = reinterpret_cast<const f32x4*>(pwn)[tc * 2 + 1];
#pragma unroll
  for (int r = 0; r < 8; ++r) {
    const f32x4 v0 = reinterpret_cast<const f32x4*>(aggv + (row0 + r) * 128 + tc * 8)[0];
    const f32x4 v1 = reinterpret_cast<const f32x4*>(aggv + (row0 + r) * 128 + tc * 8)[1];
    f32x4 o0 = acc0[r] + b0 + v0;
    f32x4 o1 = acc1[r] + b1 + v1;
#pragma unroll
    for (int c = 0; c < 4; ++c) { o0[c] = fmaxf(o0[c], 0.f); o1[c] = fmaxf(o1[c], 0.f); }
    f32x4* outp = reinterpret_cast<f32x4*>(outc + (row0 + r) * 128 + tc * 8);
    outp[0] = o0; outp[1] = o1;
    float sp = dotv(o0, p0) + dotv(o1, p1);
#pragma unroll
    for (int d = 1; d < 16; d <<= 1) sp += __shfl_xor(sp, d, 16);
    if (tc == 0) score[row0 + r] = tanhf(sp);
  }
}

// ===== fused setup: init deg/nmap/bn2 + pwn + Wc[t,i]=sum_d Wq[t,d]*We[i,d] =====
__global__ __launch_bounds__(256) void setup_kernel(
    const float* __restrict__ pool_w, float* __restrict__ pwn,
    const float* __restrict__ Wq, const float* __restrict__ bq,
    const float* __restrict__ We, float* __restrict__ Wc, float* __restrict__ bc,
    int* __restrict__ deg, int* __restrict__ nmap, float* __restrict__ bn2) {
  const int blk = blockIdx.x;
  const int t = threadIdx.x;
  if (blk < 256) {                 // init
    const int i = blk * 256 + t;
    deg[i] = 0; nmap[i] = -1;
    if (i < 256) bn2[i] = 0.f;     // bnsum[128]+bnsq[128]
  } else if (blk == 256) {         // pool_w normalization
    __shared__ float red[128];
    if (t < 128) {
      const float vv = pool_w[t];
      red[t] = vv * vv;
    }
    __syncthreads();
    for (int d = 64; d > 0; d >>= 1) {
      if (t < d) red[t] += red[t + d];
      __syncthreads();
    }
    if (t < 128) pwn[t] = pool_w[t] * rsqrtf(red[0]);
  } else {                         // Wc: 2 output cols per block
    __shared__ float sWe[2][128];
    const int i = (blk - 257) * 2 + (t >> 7);   // output col
    const int tl = t & 127;
    sWe[t >> 7][tl] = We[i * 128 + tl];
    __syncthreads();
    float s = 0.f;
    for (int d = 0; d < 128; ++d) s = fmaf(Wq[tl * 128 + d], sWe[t >> 7][d], s);
    Wc[tl * 128 + i] = s;
    if (tl == 0) {
      float sb = 0.f;
      for (int d = 0; d < 128; ++d) sb = fmaf(bq[d], sWe[t >> 7][d], sb);
      bc[i] = sb;
    }
  }
}

// ---------------- CSR build ----------------
__global__ void deg_kernel(const int* __restrict__ dst, int* __restrict__ deg) {
  const int e = blockIdx.x * 256 + threadIdx.x;
  atomicAdd(&deg[dst[e]], 1);
}

__global__ __launch_bounds__(1024) void scan_kernel(const int* __restrict__ deg,
                                                    int* __restrict__ offs,
                                                    int* __restrict__ woff) {
  __shared__ int part[1024];
  const int t = threadIdx.x;
  const int base = t * 64;
  int s = 0;
  for (int j = 0; j < 64; ++j) s += deg[base + j];
  part[t] = s;
  __syncthreads();
  for (int d = 1; d < 1024; d <<= 1) {
    const int add = (t >= d) ? part[t - d] : 0;
    __syncthreads();
    part[t] += add;
    __syncthreads();
  }
  int run = part[t] - s;
  for (int j = 0; j < 64; ++j) {
    offs[base + j] = run; woff[base + j] = run;
    run += deg[base + j];
  }
  if (t == 1023) offs[NODES] = run;
}

// sorted edge array: packed (src<<32 | e)
__global__ void scatter_kernel(const int* __restrict__ dst, const int* __restrict__ src,
                               int* __restrict__ woff, long long* __restrict__ srt) {
  const int e = blockIdx.x * 256 + threadIdx.x;
  const int pos = atomicAdd(&woff[dst[e]], 1);
  srt[pos] = ((long long)src[e] << 32) | (unsigned)e;
}

// ========== fused attention: 4x16-lane groups per wave, 2 edges/group in flight ==========
// kv interleaved [node][256]; ea NONTEMPORAL (keep kv/q/qw L2-resident); DPP row reduce;
// next-iteration srt prefetched during compute.
__global__ __launch_bounds__(256) void attn_v7(
    const float* __restrict__ q, const float* __restrict__ kv,
    const float* __restrict__ qw, const float* __restrict__ ea,
    const float* __restrict__ be, const long long* __restrict__ srt,
    const int* __restrict__ offs, float* __restrict__ aggv,
    float* __restrict__ agge) {
  int b = blockIdx.x;
  b = (b & 7) * 2048 + (b >> 3);                        // XCD-bijective swizzle (16384%8==0)
  const int wid = b * 4 + (threadIdx.x >> 6);
  const int lane = threadIdx.x & 63;
  const int g = lane >> 4;        // edge-group 0..3
  const int l = lane & 15;        // lane within group; owns dims 8l..8l+7
  const f32x4* q4  = reinterpret_cast<const f32x4*>(q)  + (size_t)wid * 32;
  const f32x4* qw4 = reinterpret_cast<const f32x4*>(qw) + (size_t)wid * 32;
  const f32x4* be4 = reinterpret_cast<const f32x4*>(be);
  const f32x4 qv0 = q4[2 * l],  qv1 = q4[2 * l + 1];
  const f32x4 qwv0 = qw4[2 * l], qwv1 = qw4[2 * l + 1];
  const float SCALE = 0.08838834764831845f;             // 1/sqrt(128)
  const float qbeS = row16_sum(dotv(qv0, be4[2 * l]) + dotv(qv1, be4[2 * l + 1])) * SCALE;

  const f32x4* kv4 = reinterpret_cast<const f32x4*>(kv);
  const f32x4* ea4 = reinterpret_cast<const f32x4*>(ea);
  float denom = 0.f;
  f32x4 av0 = (f32x4)(0.f), av1 = (f32x4)(0.f), ag0 = (f32x4)(0.f), ag1 = (f32x4)(0.f);
  const int e0 = offs[wid], e1 = offs[wid + 1];
  int p = e0 + g;
  long long pkA = 0, pkB = 0;
  if (p < e1) {
    pkA = ntloadll(srt + p);
    pkB = ((p + 4) < e1) ? ntloadll(srt + p + 4) : pkA;
  }
  while (p < e1) {
    const bool h2 = (p + 4) < e1;
    const int pn = p + 8;
    // prefetch next iteration's packed (src,e) pair before the heavy compute
    long long nA = 0, nB = 0;
    if (pn < e1) {
      nA = ntloadll(srt + pn);
      nB = ((pn + 4) < e1) ? ntloadll(srt + pn + 4) : nA;
    }
    const int eA = (int)pkA, sA = (int)(pkA >> 32);
    const int eB = (int)pkB, sB = (int)(pkB >> 32);
    const f32x4* kvA = kv4 + (size_t)sA * 64 + 2 * l;
    const f32x4* kvB = kv4 + (size_t)sB * 64 + 2 * l;
    const f32x4 kA0 = kvA[0], kA1 = kvA[1], vA0 = kvA[32], vA1 = kvA[33];
    const f32x4 kB0 = kvB[0], kB1 = kvB[1], vB0 = kvB[32], vB1 = kvB[33];
    const f32x4 fA0 = ntload4(ea4 + (size_t)eA * 32 + 2 * l);
    const f32x4 fA1 = ntload4(ea4 + (size_t)eA * 32 + 2 * l + 1);
    const f32x4 fB0 = ntload4(ea4 + (size_t)eB * 32 + 2 * l);
    const f32x4 fB1 = ntload4(ea4 + (size_t)eB * 32 + 2 * l + 1);
    float pA = dotv(qv0, kA0) + dotv(qv1, kA1) + dotv(qwv0, fA0) + dotv(qwv1, fA1);
    float pB = dotv(qv0, kB0) + dotv(qv1, kB1) + dotv(qwv0, fB0) + dotv(qwv1, fB1);
    pA = row16_sum(pA);                                  // DPP, VALU-speed
    pB = row16_sum(pB);
    const float wA = __expf(fmaf(pA, SCALE, qbeS));
    const float wB = h2 ? __expf(fmaf(pB, SCALE, qbeS)) : 0.f;
    denom += wA + wB;
    av0 += wA * vA0 + wB * vB0;
    av1 += wA * vA1 + wB * vB1;
    ag0 += wA * fA0 + wB * fB0;
    ag1 += wA * fA1 + wB * fB1;
    pkA = nA; pkB = nB; p = pn;
  }
  // cross-group combine (xor 16, 32)
#pragma unroll
  for (int d = 16; d < 64; d <<= 1) {
    denom += __shfl_xor(denom, d, 64);
#pragma unroll
    for (int c = 0; c < 4; ++c) {
      av0[c] += __shfl_xor(av0[c], d, 64);
      av1[c] += __shfl_xor(av1[c], d, 64);
      ag0[c] += __shfl_xor(ag0[c], d, 64);
      ag1[c] += __shfl_xor(ag1[c], d, 64);
    }
  }
  if (g == 0) {
    const float inv = 1.f / (denom + 1e-16f);
    f32x4* aggv4 = reinterpret_cast<f32x4*>(aggv) + (size_t)wid * 32;
    f32x4* agge4 = reinterpret_cast<f32x4*>(agge) + (size_t)wid * 32;
    aggv4[2 * l]     = av0 * inv;
    aggv4[2 * l + 1] = av1 * inv;
    agge4[2 * l]     = ag0 * inv;
    agge4[2 * l + 1] = ag1 * inv;
  }
}

// -------- per-graph top-k via bitonic sort (desc, tie -> lower index); writes nmap --------
__global__ __launch_bounds__(1024) void topk_kernel(
    const float* __restrict__ score, int* __restrict__ perm,
    float* __restrict__ tops, float* __restrict__ batchf, int* __restrict__ nmap) {
  __shared__ float ss[1024];
  __shared__ int si[1024];
  const int b = blockIdx.x, t = threadIdx.x;
  ss[t] = score[b * 1024 + t];
  si[t] = t;
  __syncthreads();
  for (int size = 2; size <= 1024; size <<= 1) {
    for (int stride = size >> 1; stride > 0; stride >>= 1) {
      const int j = t ^ stride;
      if (j > t) {
        const float s1 = ss[t], s2 = ss[j];
        const int i1 = si[t], i2 = si[j];
        const bool bj = (s2 > s1) || (s2 == s1 && i2 < i1);
        const bool dir = ((t & size) == 0);
        if (dir ? bj : !bj) { ss[t] = s2; ss[j] = s1; si[t] = i2; si[j] = i1; }
      }
      __syncthreads();
    }
  }
  if (t < TOPK) {
    const int g = b * TOPK + t;
    perm[g] = b * 1024 + si[t];
    tops[g] = ss[t];
    batchf[g] = (float)b;
    nmap[b * 1024 + si[t]] = g;
  }
}

// ------------- gather xp = out[perm]*top_s + BN partial sums -------------
__global__ __launch_bounds__(128) void xp_kernel(
    const float* __restrict__ outc, const int* __restrict__ perm,
    const float* __restrict__ tops, float* __restrict__ y,
    float* __restrict__ bnsum, float* __restrict__ bnsq) {
  const int t = threadIdx.x;
  const int r0 = blockIdx.x * 128;
  float s = 0.f, s2 = 0.f;
  for (int i = 0; i < 128; ++i) {
    const int r = r0 + i;
    const int g = perm[r];
    const float val = outc[(size_t)g * DIM + t] * tops[r];
    y[(size_t)r * DIM + t] = val;
    s += val;
    s2 = fmaf(val, val, s2);
  }
  atomicAdd(&bnsum[t], s);
  atomicAdd(&bnsq[t], s2);
}

// BN finalize folded into apply: each thread derives a/c for its 4 columns
__global__ __launch_bounds__(256) void bnapply_v2(
    float* __restrict__ y, const float* __restrict__ bnsum, const float* __restrict__ bnsq,
    const float* __restrict__ gamma, const float* __restrict__ beta) {
  const size_t i4 = (size_t)blockIdx.x * 256 + threadIdx.x;   // BKR*32 float4s
  const int c4 = (int)(i4 & 31);
  f32x4 a, c;
#pragma unroll
  for (int j = 0; j < 4; ++j) {
    const int col = c4 * 4 + j;
    const float mu = bnsum[col] * (1.f / BKR);
    const float var = bnsq[col] * (1.f / BKR) - mu * mu;
    const float aa = gamma[col] * rsqrtf(var + 1e-5f);
    a[j] = aa;
    c[j] = beta[col] - mu * aa;
  }
  f32x4 v = reinterpret_cast<f32x4*>(y)[i4];
#pragma unroll
  for (int j = 0; j < 4; ++j) v[j] = fmaf(v[j], a[j], c[j]);
  reinterpret_cast<f32x4*>(y)[i4] = v;
}

// ---------------- fused edge remap + valid + masked edge_attr ----------------
__global__ __launch_bounds__(256) void efnea_kernel(
    const int* __restrict__ srcArr, const int* __restrict__ dstArr,
    const int* __restrict__ nm, const float* __restrict__ ea,
    float* __restrict__ nei, float* __restrict__ validf, float* __restrict__ nea) {
  const int row = blockIdx.x * 8 + (threadIdx.x >> 5);
  const int lane = threadIdx.x & 31;
  const int ns = nm[srcArr[row]];
  const int nd = nm[dstArr[row]];
  const bool val = (ns >= 0) && (nd >= 0);
  if (lane == 0) {
    nei[row] = val ? (float)ns : -1.f;
    nei[NEDGE + row] = val ? (float)nd : -1.f;
    validf[row] = val ? 1.f : 0.f;
  }
  const size_t i4 = (size_t)row * 32 + lane;
  f32x4 v = (f32x4)(0.f);
  if (val) v = ntload4(reinterpret_cast<const f32x4*>(ea) + i4);
  ntstore4(reinterpret_cast<f32x4*>(nea) + i4, v);
}

// ---------------- launch ----------------
extern "C" void kernel_launch(void* const* d_in, const int* in_sizes, int n_in,
                              void* d_out, int out_size, void* d_ws, size_t ws_size,
                              hipStream_t stream) {
  const float* x     = (const float*)d_in[0];
  const int*   eidx  = (const int*)d_in[1];
  const float* eattr = (const float*)d_in[2];
  const float* Wq = (const float*)d_in[4];  const float* bq = (const float*)d_in[5];
  const float* Wk = (const float*)d_in[6];  const float* bk = (const float*)d_in[7];
  const float* Wv = (const float*)d_in[8];  const float* bv = (const float*)d_in[9];
  const float* We = (const float*)d_in[10]; const float* be = (const float*)d_in[11];
  const float* Ws = (const float*)d_in[12]; const float* bs = (const float*)d_in[13];
  const float* pool_w = (const float*)d_in[14];
  const float* gamma  = (const float*)d_in[15];
  const float* beta   = (const float*)d_in[16];

  const int* srcArr = eidx;
  const int* dstArr = eidx + NEDGE;

  float* out = (float*)d_out;
  // output layout (floats)
  float* y      = out;                                   // BKR*128
  float* nei    = out + (size_t)BKR * DIM;               // 2*NEDGE
  float* nea    = nei + 2 * (size_t)NEDGE;               // NEDGE*128
  float* batchf = nea + (size_t)NEDGE * DIM;             // BKR
  float* validf = batchf + BKR;                          // NEDGE

  // big node arrays staged inside the (not-yet-written) nea region: 7 x NM = 224MB
  float* q    = nea + 0 * NM;
  float* kv   = nea + 1 * NM;   // 2*NM (k|v interleaved, 256 floats/row)
  float* qw   = nea + 3 * NM;
  float* aggv = nea + 4 * NM;
  float* agge = nea + 5 * NM;
  float* outc = nea + 6 * NM;

  // workspace layout (small)
  char* w = (char*)d_ws;
  size_t off = 0;
  float* score= (float*)(w + off); off += (size_t)NODES * 4;
  float* pwn  = (float*)(w + off); off += 128 * 4;
  float* Wc   = (float*)(w + off); off += 128 * 128 * 4;
  float* bc   = (float*)(w + off); off += 128 * 4;
  float* tops = (float*)(w + off); off += (size_t)BKR * 4;
  float* bnsum= (float*)(w + off); off += 128 * 4;
  float* bnsq = (float*)(w + off); off += 128 * 4;
  int* deg    = (int*)(w + off); off += (size_t)NODES * 4;
  int* offs   = (int*)(w + off); off += ((size_t)NODES + 8) * 4;
  int* woff   = (int*)(w + off); off += (size_t)NODES * 4;
  int* nmap   = (int*)(w + off); off += (size_t)NODES * 4;
  int* perm   = (int*)(w + off); off += (size_t)BKR * 4;
  long long* srt = (long long*)(w + off); off += (size_t)NEDGE * 8;

  // fused setup: init + pwn + Wc  (blocks: 256 init | 1 pwn | 64 Wc)
  setup_kernel<<<321, 256, 0, stream>>>(pool_w, pwn, Wq, bq, We, Wc, bc,
                                        deg, nmap, (float*)bnsum);

  // node-level linear layers (q, k|v, qW) in one launch
  gemm_multi<<<4 * 256, 512, 0, stream>>>(
      x, Wq, bq, q, Wk, bk, Wv, bv, kv, Wc, bc, qw);

  // CSR by dst
  deg_kernel<<<NEDGE / 256, 256, 0, stream>>>(dstArr, deg);
  scan_kernel<<<1, 1024, 0, stream>>>(deg, offs, woff);
  scatter_kernel<<<NEDGE / 256, 256, 0, stream>>>(dstArr, srcArr, woff, srt);

  // fused attention on raw edge_attr (NT stream), DPP reduce + srt prefetch
  attn_v7<<<NODES / 4, 256, 0, stream>>>(q, kv, qw, eattr, be, srt, offs, aggv, agge);

  // final conv output (+ fused skip GEMM) + score
  gemm_final2<<<NODES / 128, 256, 0, stream>>>(agge, We, x, Ws, be, bs, aggv, pwn,
                                               outc, score);

  // top-k pooling (writes perm/tops/batch + nmap)
  topk_kernel<<<NB, 1024, 0, stream>>>(score, perm, tops, batchf, nmap);

  // xp gather + BN (must finish with outc before nea overwrite)
  xp_kernel<<<BKR / 128, 128, 0, stream>>>(outc, perm, tops, y, bnsum, bnsq);
  bnapply_v2<<<(BKR * 32) / 256, 256, 0, stream>>>(y, bnsum, bnsq, gamma, beta);

  // fused edge remap + masked edge_attr (overwrites staging region last)
  efnea_kernel<<<NEDGE / 8, 256, 0, stream>>>(srcArr, dstArr, nmap, eattr, nei, validf, nea);
}

// Round 9
// 641.428 us; speedup vs baseline: 1.1677x; 1.1298x over previous
//
#include <hip/hip_runtime.h>
#include <cstddef>
#include <cstdint>

#define NODES 65536      // B*N
#define NEDGE 1048576    // B*E_PER
#define NB    64
#define NPER  1024
#define TOPK  512
#define BKR   32768      // NB*TOPK
#define DIM   128
#define NM    ((size_t)NODES * DIM)   // floats per node-array

typedef float f32x4 __attribute__((ext_vector_type(4)));

__device__ __forceinline__ f32x4 ntload4(const f32x4* p) {
  return __builtin_nontemporal_load(p);
}
__device__ __forceinline__ void ntstore4(f32x4* p, f32x4 v) {
  __builtin_nontemporal_store(v, p);
}
__device__ __forceinline__ long long ntloadll(const long long* p) {
  return __builtin_nontemporal_load(p);
}
__device__ __forceinline__ float dotv(f32x4 a, f32x4 b) {
  return fmaf(a.x, b.x, fmaf(a.y, b.y, fmaf(a.z, b.z, a.w * b.w)));
}

// ---- DPP 16-lane sum (VALU-speed, stays within one 16-lane group) ----
template <int CTRL>
__device__ __forceinline__ float dpp_addf(float x) {
  const int y = __builtin_amdgcn_update_dpp(0, __float_as_int(x), CTRL, 0xF, 0xF, true);
  return x + __int_as_float(y);
}
__device__ __forceinline__ float row16_sum(float x) {
  x = dpp_addf<0xB1>(x);    // quad_perm [1,0,3,2]  (xor 1)
  x = dpp_addf<0x4E>(x);    // quad_perm [2,3,0,1]  (xor 2)
  x = dpp_addf<0x124>(x);   // row_ror:4
  x = dpp_addf<0x128>(x);   // row_ror:8
  return x;
}

// ============ Wc precompute: Wc[t,i] = sum_d Wq[t,d]*We[i,d]; bc = bq@We^T ============
__global__ __launch_bounds__(512) void wc_kernel(
    const float* __restrict__ Wq, const float* __restrict__ bq,
    const float* __restrict__ We, float* __restrict__ Wc, float* __restrict__ bc) {
  __shared__ float sWe[4][128];
  const int t = threadIdx.x;
  const int sub = t >> 7;
  const int tl = t & 127;
  const int i = blockIdx.x * 4 + sub;
  sWe[sub][tl] = We[i * 128 + tl];
  __syncthreads();
  float s = 0.f;
  for (int d = 0; d < 128; ++d) s = fmaf(Wq[tl * 128 + d], sWe[sub][d], s);
  Wc[tl * 128 + i] = s;
  if (tl == 0) {
    float sb = 0.f;
    for (int d = 0; d < 128; ++d) sb = fmaf(bq[d], sWe[sub][d], sb);
    bc[i] = sb;
  }
}

// ================= shared GEMM core: Out[row0..row0+7] = A-rows @ sW + bias =============
__device__ __forceinline__ void gemm_core(
    const float* __restrict__ A, const f32x4* __restrict__ sW,
    const float* __restrict__ bias, float* __restrict__ Out,
    size_t row0, int ostride, int tc) {
  const float* a0 = A + row0 * 128;
  f32x4 acc0[8], acc1[8];
#pragma unroll
  for (int r = 0; r < 8; ++r) { acc0[r] = (f32x4)(0.f); acc1[r] = (f32x4)(0.f); }
#pragma unroll 4
  for (int k4 = 0; k4 < 32; ++k4) {
    f32x4 a[8];
#pragma unroll
    for (int r = 0; r < 8; ++r)
      a[r] = *reinterpret_cast<const f32x4*>(a0 + r * 128 + k4 * 4);
#pragma unroll
    for (int kk = 0; kk < 4; ++kk) {
      const f32x4 w0 = sW[(k4 * 4 + kk) * 32 + tc * 2];
      const f32x4 w1 = sW[(k4 * 4 + kk) * 32 + tc * 2 + 1];
#pragma unroll
      for (int r = 0; r < 8; ++r) {
        const float av = a[r][kk];
        acc0[r] += av * w0;
        acc1[r] += av * w1;
      }
    }
  }
  const f32x4 b0 = reinterpret_cast<const f32x4*>(bias)[tc * 2];
  const f32x4 b1 = reinterpret_cast<const f32x4*>(bias)[tc * 2 + 1];
#pragma unroll
  for (int r = 0; r < 8; ++r) {
    f32x4* outp = reinterpret_cast<f32x4*>(Out + (row0 + r) * (size_t)ostride + tc * 8);
    outp[0] = acc0[r] + b0;
    outp[1] = acc1[r] + b1;
  }
}

// ============ MEGA kernel: 4 GEMMs + per-graph CSR + nmap init + pwn, ONE launch ========
// blocks [0,1024): node GEMMs   [1024,1088): per-graph CSR   [1088,1120): init   1120: pwn
__global__ __launch_bounds__(512) void mega_kernel(
    const float* __restrict__ x,
    const float* __restrict__ Wq, const float* __restrict__ bq, float* __restrict__ q,
    const float* __restrict__ Wk, const float* __restrict__ bk,
    const float* __restrict__ Wv, const float* __restrict__ bv, float* __restrict__ kv,
    const float* __restrict__ Wc, const float* __restrict__ bc, float* __restrict__ qw,
    const int* __restrict__ srcArr, const int* __restrict__ dstArr,
    int* __restrict__ offs, long long* __restrict__ srt,
    const float* __restrict__ pool_w, float* __restrict__ pwn,
    int* __restrict__ nmap, float* __restrict__ bn2) {
  __shared__ __align__(16) char smem[65536];
  const int blk = blockIdx.x;
  const int t = threadIdx.x;

  if (blk < 1024) {                       // ---- GEMM ----
    f32x4* sW = reinterpret_cast<f32x4*>(smem);
    const int which = blk >> 8;
    const int bid = blk & 255;
    const float* W; const float* bias; float* Out; int ostride = 128;
    if (which == 0)      { W = Wq; bias = bq; Out = q; }
    else if (which == 1) { W = Wk; bias = bk; Out = kv;       ostride = 256; }
    else if (which == 2) { W = Wv; bias = bv; Out = kv + 128; ostride = 256; }
    else                 { W = Wc; bias = bc; Out = qw; }
    const f32x4* W4 = reinterpret_cast<const f32x4*>(W);
#pragma unroll
    for (int i = 0; i < 8; ++i) sW[t + i * 512] = W4[t + i * 512];
    __syncthreads();
    gemm_core(x, sW, bias, Out, (size_t)bid * 256 + (t >> 4) * 8, ostride, t & 15);
  } else if (blk < 1088) {                // ---- per-graph CSR (LDS count+scan+scatter) ----
    int* cnt = reinterpret_cast<int*>(smem);          // [1024]
    int* aux = cnt + 1024;                            // [512]
    const int g = blk - 1024;
    const int ebase = g * 16384;
    cnt[t] = 0; cnt[t + 512] = 0;
    __syncthreads();
#pragma unroll 4
    for (int j = 0; j < 32; ++j) {
      const int e = ebase + j * 512 + t;
      atomicAdd(&cnt[dstArr[e] & 1023], 1);
    }
    __syncthreads();
    const int two0 = cnt[2 * t], two1 = cnt[2 * t + 1];
    const int part = two0 + two1;
    aux[t] = part;
    __syncthreads();
    for (int d = 1; d < 512; d <<= 1) {
      const int add = (t >= d) ? aux[t - d] : 0;
      __syncthreads();
      aux[t] += add;
      __syncthreads();
    }
    const int excl2 = aux[t] - part;      // exclusive prefix over node pairs
    __syncthreads();
    offs[g * 1024 + 2 * t]     = ebase + excl2;
    offs[g * 1024 + 2 * t + 1] = ebase + excl2 + two0;
    cnt[2 * t] = excl2;
    cnt[2 * t + 1] = excl2 + two0;
    if (g == 0 && t == 0) offs[NODES] = NEDGE;
    __syncthreads();
#pragma unroll 4
    for (int j = 0; j < 32; ++j) {
      const int e = ebase + j * 512 + t;
      const int d = dstArr[e] & 1023;
      const int pos = atomicAdd(&cnt[d], 1);
      srt[ebase + pos] = ((long long)srcArr[e] << 32) | (unsigned)e;
    }
  } else if (blk < 1120) {                // ---- nmap init (+bn2) ----
    const int base = ((blk - 1088) * 512 + t) * 4;
    nmap[base] = -1; nmap[base + 1] = -1; nmap[base + 2] = -1; nmap[base + 3] = -1;
    if (blk == 1088 && t < 256) bn2[t] = 0.f;   // bnsum[128]+bnsq[128]
  } else {                                // ---- pwn ----
    float* red = reinterpret_cast<float*>(smem);
    if (t < 128) {
      const float vv = pool_w[t];
      red[t] = vv * vv;
    }
    __syncthreads();
    for (int d = 64; d > 0; d >>= 1) {
      if (t < d) red[t] += red[t + d];
      __syncthreads();
    }
    if (t < 128) pwn[t] = pool_w[t] * rsqrtf(red[0]);
  }
}

// ====== final: outc = relu(agge@We + x@Ws + be + bs + aggv); score epilogue ======
__global__ __launch_bounds__(256) void gemm_final2(
    const float* __restrict__ agge, const float* __restrict__ We,
    const float* __restrict__ x,    const float* __restrict__ Ws,
    const float* __restrict__ be,   const float* __restrict__ bs,
    const float* __restrict__ aggv, const float* __restrict__ pwn,
    float* __restrict__ outc, float* __restrict__ score) {
  __shared__ f32x4 sW[128 * 32];
  const int t = threadIdx.x;
  const int tc = t & 15;
  const size_t row0 = (size_t)blockIdx.x * 128 + (t >> 4) * 8;
  f32x4 acc0[8], acc1[8];
#pragma unroll
  for (int r = 0; r < 8; ++r) { acc0[r] = (f32x4)(0.f); acc1[r] = (f32x4)(0.f); }

#pragma unroll
  for (int phase = 0; phase < 2; ++phase) {
    const float* W = phase ? Ws : We;
    const float* A = phase ? x : agge;
    const f32x4* W4 = reinterpret_cast<const f32x4*>(W);
    if (phase) __syncthreads();
#pragma unroll
    for (int i = 0; i < 16; ++i) sW[t + i * 256] = W4[t + i * 256];
    __syncthreads();
    const float* a0 = A + row0 * 128;
#pragma unroll 4
    for (int k4 = 0; k4 < 32; ++k4) {
      f32x4 a[8];
#pragma unroll
      for (int r = 0; r < 8; ++r)
        a[r] = *reinterpret_cast<const f32x4*>(a0 + r * 128 + k4 * 4);
#pragma unroll
      for (int kk = 0; kk < 4; ++kk) {
        const f32x4 w0 = sW[(k4 * 4 + kk) * 32 + tc * 2];
        const f32x4 w1 = sW[(k4 * 4 + kk) * 32 + tc * 2 + 1];
#pragma unroll
        for (int r = 0; r < 8; ++r) {
          const float av = a[r][kk];
          acc0[r] += av * w0;
          acc1[r] += av * w1;
        }
      }
    }
  }
  const f32x4 b0 = reinterpret_cast<const f32x4*>(be)[tc * 2] +
                   reinterpret_cast<const f32x4*>(bs)[tc * 2];
  const f32x4 b1 = reinterpret_cast<const f32x4*>(be)[tc * 2 + 1] +
                   reinterpret_cast<const f32x4*>(bs)[tc * 2 + 1];
  const f32x4 p0 = reinterpret_cast<const f32x4*>(pwn)[tc * 2];
  const f32x4 p1 = reinterpret_cast<const f32x4*>(pwn)[tc * 2 + 1];
#pragma unroll
  for (int r = 0; r < 8; ++r) {
    const f32x4 v0 = reinterpret_cast<const f32x4*>(aggv + (row0 + r) * 128 + tc * 8)[0];
    const f32x4 v1 = reinterpret_cast<const f32x4*>(aggv + (row0 + r) * 128 + tc * 8)[1];
    f32x4 o0 = acc0[r] + b0 + v0;
    f32x4 o1 = acc1[r] + b1 + v1;
#pragma unroll
    for (int c = 0; c < 4; ++c) { o0[c] = fmaxf(o0[c], 0.f); o1[c] = fmaxf(o1[c], 0.f); }
    f32x4* outp = reinterpret_cast<f32x4*>(outc + (row0 + r) * 128 + tc * 8);
    outp[0] = o0; outp[1] = o1;
    float sp = dotv(o0, p0) + dotv(o1, p1);
#pragma unroll
    for (int d = 1; d < 16; d <<= 1) sp += __shfl_xor(sp, d, 16);
    if (tc == 0) score[row0 + r] = tanhf(sp);
  }
}

// ========== fused attention: 4x16-lane groups per wave, 2 edges/group in flight ==========
__global__ __launch_bounds__(256) void attn_v7(
    const float* __restrict__ q, const float* __restrict__ kv,
    const float* __restrict__ qw, const float* __restrict__ ea,
    const float* __restrict__ be, const long long* __restrict__ srt,
    const int* __restrict__ offs, float* __restrict__ aggv,
    float* __restrict__ agge) {
  int b = blockIdx.x;
  b = (b & 7) * 2048 + (b >> 3);                        // XCD-bijective swizzle (16384%8==0)
  const int wid = b * 4 + (threadIdx.x >> 6);
  const int lane = threadIdx.x & 63;
  const int g = lane >> 4;        // edge-group 0..3
  const int l = lane & 15;        // lane within group; owns dims 8l..8l+7
  const f32x4* q4  = reinterpret_cast<const f32x4*>(q)  + (size_t)wid * 32;
  const f32x4* qw4 = reinterpret_cast<const f32x4*>(qw) + (size_t)wid * 32;
  const f32x4* be4 = reinterpret_cast<const f32x4*>(be);
  const f32x4 qv0 = q4[2 * l],  qv1 = q4[2 * l + 1];
  const f32x4 qwv0 = qw4[2 * l], qwv1 = qw4[2 * l + 1];
  const float SCALE = 0.08838834764831845f;             // 1/sqrt(128)
  const float qbeS = row16_sum(dotv(qv0, be4[2 * l]) + dotv(qv1, be4[2 * l + 1])) * SCALE;

  const f32x4* kv4 = reinterpret_cast<const f32x4*>(kv);
  const f32x4* ea4 = reinterpret_cast<const f32x4*>(ea);
  float denom = 0.f;
  f32x4 av0 = (f32x4)(0.f), av1 = (f32x4)(0.f), ag0 = (f32x4)(0.f), ag1 = (f32x4)(0.f);
  const int e0 = offs[wid], e1 = offs[wid + 1];
  int p = e0 + g;
  long long pkA = 0, pkB = 0;
  if (p < e1) {
    pkA = ntloadll(srt + p);
    pkB = ((p + 4) < e1) ? ntloadll(srt + p + 4) : pkA;
  }
  while (p < e1) {
    const bool h2 = (p + 4) < e1;
    const int pn = p + 8;
    long long nA = 0, nB = 0;
    if (pn < e1) {
      nA = ntloadll(srt + pn);
      nB = ((pn + 4) < e1) ? ntloadll(srt + pn + 4) : nA;
    }
    const int eA = (int)pkA, sA = (int)(pkA >> 32);
    const int eB = (int)pkB, sB = (int)(pkB >> 32);
    const f32x4* kvA = kv4 + (size_t)sA * 64 + 2 * l;
    const f32x4* kvB = kv4 + (size_t)sB * 64 + 2 * l;
    const f32x4 kA0 = kvA[0], kA1 = kvA[1], vA0 = kvA[32], vA1 = kvA[33];
    const f32x4 kB0 = kvB[0], kB1 = kvB[1], vB0 = kvB[32], vB1 = kvB[33];
    const f32x4 fA0 = ntload4(ea4 + (size_t)eA * 32 + 2 * l);
    const f32x4 fA1 = ntload4(ea4 + (size_t)eA * 32 + 2 * l + 1);
    const f32x4 fB0 = ntload4(ea4 + (size_t)eB * 32 + 2 * l);
    const f32x4 fB1 = ntload4(ea4 + (size_t)eB * 32 + 2 * l + 1);
    float pA = dotv(qv0, kA0) + dotv(qv1, kA1) + dotv(qwv0, fA0) + dotv(qwv1, fA1);
    float pB = dotv(qv0, kB0) + dotv(qv1, kB1) + dotv(qwv0, fB0) + dotv(qwv1, fB1);
    pA = row16_sum(pA);
    pB = row16_sum(pB);
    const float wA = __expf(fmaf(pA, SCALE, qbeS));
    const float wB = h2 ? __expf(fmaf(pB, SCALE, qbeS)) : 0.f;
    denom += wA + wB;
    av0 += wA * vA0 + wB * vB0;
    av1 += wA * vA1 + wB * vB1;
    ag0 += wA * fA0 + wB * fB0;
    ag1 += wA * fA1 + wB * fB1;
    pkA = nA; pkB = nB; p = pn;
  }
#pragma unroll
  for (int d = 16; d < 64; d <<= 1) {
    denom += __shfl_xor(denom, d, 64);
#pragma unroll
    for (int c = 0; c < 4; ++c) {
      av0[c] += __shfl_xor(av0[c], d, 64);
      av1[c] += __shfl_xor(av1[c], d, 64);
      ag0[c] += __shfl_xor(ag0[c], d, 64);
      ag1[c] += __shfl_xor(ag1[c], d, 64);
    }
  }
  if (g == 0) {
    const float inv = 1.f / (denom + 1e-16f);
    f32x4* aggv4 = reinterpret_cast<f32x4*>(aggv) + (size_t)wid * 32;
    f32x4* agge4 = reinterpret_cast<f32x4*>(agge) + (size_t)wid * 32;
    aggv4[2 * l]     = av0 * inv;
    aggv4[2 * l + 1] = av1 * inv;
    agge4[2 * l]     = ag0 * inv;
    agge4[2 * l + 1] = ag1 * inv;
  }
}

// ===== fused top-k (bitonic, desc, tie->lower idx) + xp gather + BN partial sums =====
__global__ __launch_bounds__(1024) void topkxp_kernel(
    const float* __restrict__ score, const float* __restrict__ outc,
    float* __restrict__ y, float* __restrict__ batchf, int* __restrict__ nmap,
    float* __restrict__ bnsum, float* __restrict__ bnsq) {
  __shared__ float ss[1024];
  __shared__ int si[1024];
  const int b = blockIdx.x, t = threadIdx.x;
  ss[t] = score[b * 1024 + t];
  si[t] = t;
  __syncthreads();
  for (int size = 2; size <= 1024; size <<= 1) {
    for (int stride = size >> 1; stride > 0; stride >>= 1) {
      const int j = t ^ stride;
      if (j > t) {
        const float s1 = ss[t], s2 = ss[j];
        const int i1 = si[t], i2 = si[j];
        const bool bj = (s2 > s1) || (s2 == s1 && i2 < i1);
        const bool dir = ((t & size) == 0);
        if (dir ? bj : !bj) { ss[t] = s2; ss[j] = s1; si[t] = i2; si[j] = i1; }
      }
      __syncthreads();
    }
  }
  if (t < TOPK) {
    batchf[b * TOPK + t] = (float)b;
    nmap[b * 1024 + si[t]] = b * TOPK + t;
  }
  __syncthreads();
  // xp phase: 512 rows x 128 cols, 1024 threads (8 row-slots x 128 cols)
  const int c = t & 127;
  const int rbase = t >> 7;              // 0..7
  float s = 0.f, s2 = 0.f;
  for (int i = 0; i < 64; ++i) {
    const int r = rbase + 8 * i;         // 0..511
    const int gnode = b * 1024 + si[r];
    const float val = outc[(size_t)gnode * DIM + c] * ss[r];
    y[((size_t)b * TOPK + r) * DIM + c] = val;
    s += val;
    s2 = fmaf(val, val, s2);
  }
  atomicAdd(&bnsum[c], s);
  atomicAdd(&bnsq[c], s2);
}

// BN finalize folded into apply
__global__ __launch_bounds__(256) void bnapply_v2(
    float* __restrict__ y, const float* __restrict__ bnsum, const float* __restrict__ bnsq,
    const float* __restrict__ gamma, const float* __restrict__ beta) {
  const size_t i4 = (size_t)blockIdx.x * 256 + threadIdx.x;   // BKR*32 float4s
  const int c4 = (int)(i4 & 31);
  f32x4 a, c;
#pragma unroll
  for (int j = 0; j < 4; ++j) {
    const int col = c4 * 4 + j;
    const float mu = bnsum[col] * (1.f / BKR);
    const float var = bnsq[col] * (1.f / BKR) - mu * mu;
    const float aa = gamma[col] * rsqrtf(var + 1e-5f);
    a[j] = aa;
    c[j] = beta[col] - mu * aa;
  }
  f32x4 v = reinterpret_cast<f32x4*>(y)[i4];
#pragma unroll
  for (int j = 0; j < 4; ++j) v[j] = fmaf(v[j], a[j], c[j]);
  reinterpret_cast<f32x4*>(y)[i4] = v;
}

// ---------------- fused edge remap + valid + masked edge_attr ----------------
__global__ __launch_bounds__(256) void efnea_kernel(
    const int* __restrict__ srcArr, const int* __restrict__ dstArr,
    const int* __restrict__ nm, const float* __restrict__ ea,
    float* __restrict__ nei, float* __restrict__ validf, float* __restrict__ nea) {
  const int row = blockIdx.x * 8 + (threadIdx.x >> 5);
  const int lane = threadIdx.x & 31;
  const int ns = nm[srcArr[row]];
  const int nd = nm[dstArr[row]];
  const bool val = (ns >= 0) && (nd >= 0);
  if (lane == 0) {
    nei[row] = val ? (float)ns : -1.f;
    nei[NEDGE + row] = val ? (float)nd : -1.f;
    validf[row] = val ? 1.f : 0.f;
  }
  const size_t i4 = (size_t)row * 32 + lane;
  f32x4 v = (f32x4)(0.f);
  if (val) v = ntload4(reinterpret_cast<const f32x4*>(ea) + i4);
  ntstore4(reinterpret_cast<f32x4*>(nea) + i4, v);
}

// ---------------- launch ----------------
extern "C" void kernel_launch(void* const* d_in, const int* in_sizes, int n_in,
                              void* d_out, int out_size, void* d_ws, size_t ws_size,
                              hipStream_t stream) {
  const float* x     = (const float*)d_in[0];
  const int*   eidx  = (const int*)d_in[1];
  const float* eattr = (const float*)d_in[2];
  const float* Wq = (const float*)d_in[4];  const float* bq = (const float*)d_in[5];
  const float* Wk = (const float*)d_in[6];  const float* bk = (const float*)d_in[7];
  const float* Wv = (const float*)d_in[8];  const float* bv = (const float*)d_in[9];
  const float* We = (const float*)d_in[10]; const float* be = (const float*)d_in[11];
  const float* Ws = (const float*)d_in[12]; const float* bs = (const float*)d_in[13];
  const float* pool_w = (const float*)d_in[14];
  const float* gamma  = (const float*)d_in[15];
  const float* beta   = (const float*)d_in[16];

  const int* srcArr = eidx;
  const int* dstArr = eidx + NEDGE;

  float* out = (float*)d_out;
  // output layout (floats)
  float* y      = out;                                   // BKR*128
  float* nei    = out + (size_t)BKR * DIM;               // 2*NEDGE
  float* nea    = nei + 2 * (size_t)NEDGE;               // NEDGE*128
  float* batchf = nea + (size_t)NEDGE * DIM;             // BKR
  float* validf = batchf + BKR;                          // NEDGE

  // big node arrays staged inside the (not-yet-written) nea region: 7 x NM = 224MB
  float* q    = nea + 0 * NM;
  float* kv   = nea + 1 * NM;   // 2*NM (k|v interleaved, 256 floats/row)
  float* qw   = nea + 3 * NM;
  float* aggv = nea + 4 * NM;
  float* agge = nea + 5 * NM;
  float* outc = nea + 6 * NM;

  // workspace layout (small)
  char* w = (char*)d_ws;
  size_t off = 0;
  float* score= (float*)(w + off); off += (size_t)NODES * 4;
  float* pwn  = (float*)(w + off); off += 128 * 4;
  float* Wc   = (float*)(w + off); off += 128 * 128 * 4;
  float* bc   = (float*)(w + off); off += 128 * 4;
  float* bnsum= (float*)(w + off); off += 128 * 4;
  float* bnsq = (float*)(w + off); off += 128 * 4;
  int* offs   = (int*)(w + off); off += ((size_t)NODES + 8) * 4;
  int* nmap   = (int*)(w + off); off += (size_t)NODES * 4;
  long long* srt = (long long*)(w + off); off += (size_t)NEDGE * 8;

  // 1) Wc precompute (must precede mega's which==3 GEMM that reads Wc)
  wc_kernel<<<32, 512, 0, stream>>>(Wq, bq, We, Wc, bc);

  // 2) mega: 4 GEMMs + per-graph CSR + nmap init + pwn in one launch
  mega_kernel<<<1121, 512, 0, stream>>>(
      x, Wq, bq, q, Wk, bk, Wv, bv, kv, Wc, bc, qw,
      srcArr, dstArr, offs, srt, pool_w, pwn, nmap, (float*)bnsum);

  // 3) fused attention on raw edge_attr
  attn_v7<<<NODES / 4, 256, 0, stream>>>(q, kv, qw, eattr, be, srt, offs, aggv, agge);

  // 4) final conv output (+ fused skip GEMM) + score
  gemm_final2<<<NODES / 128, 256, 0, stream>>>(agge, We, x, Ws, be, bs, aggv, pwn,
                                               outc, score);

  // 5) top-k + xp gather + BN partial sums (reads outc before staging overwrite)
  topkxp_kernel<<<NB, 1024, 0, stream>>>(score, outc, y, batchf, nmap, bnsum, bnsq);

  // 6) BN apply
  bnapply_v2<<<(BKR * 32) / 256, 256, 0, stream>>>(y, bnsum, bnsq, gamma, beta);

  // 7) fused edge remap + masked edge_attr (overwrites staging region last)
  efnea_kernel<<<NEDGE / 8, 256, 0, stream>>>(srcArr, dstArr, nmap, eattr, nei, validf, nea);
}

// Round 10
// 602.567 us; speedup vs baseline: 1.2430x; 1.0645x over previous
//
#include <hip/hip_runtime.h>
#include <cstddef>
#include <cstdint>

#define NODES 65536      // B*N
#define NEDGE 1048576    // B*E_PER
#define NB    64
#define NPER  1024
#define TOPK  512
#define BKR   32768      // NB*TOPK
#define DIM   128
#define NM    ((size_t)NODES * DIM)   // floats per node-array

typedef float f32x4 __attribute__((ext_vector_type(4)));

__device__ __forceinline__ f32x4 ntload4(const f32x4* p) {
  return __builtin_nontemporal_load(p);
}
__device__ __forceinline__ void ntstore4(f32x4* p, f32x4 v) {
  __builtin_nontemporal_store(v, p);
}
__device__ __forceinline__ long long ntloadll(const long long* p) {
  return __builtin_nontemporal_load(p);
}
__device__ __forceinline__ float dotv(f32x4 a, f32x4 b) {
  return fmaf(a.x, b.x, fmaf(a.y, b.y, fmaf(a.z, b.z, a.w * b.w)));
}

// ---- DPP 16-lane sum (VALU-speed, stays within one 16-lane row) ----
template <int CTRL>
__device__ __forceinline__ float dpp_addf(float x) {
  const int y = __builtin_amdgcn_update_dpp(0, __float_as_int(x), CTRL, 0xF, 0xF, true);
  return x + __int_as_float(y);
}
__device__ __forceinline__ float row16_sum(float x) {
  x = dpp_addf<0xB1>(x);    // quad_perm [1,0,3,2]  (xor 1)
  x = dpp_addf<0x4E>(x);    // quad_perm [2,3,0,1]  (xor 2)
  x = dpp_addf<0x124>(x);   // row_ror:4
  x = dpp_addf<0x128>(x);   // row_ror:8
  return x;
}

// ============ Wc precompute: Wc[t,i] = sum_d Wq[t,d]*We[i,d]; bc = bq@We^T ============
__global__ __launch_bounds__(512) void wc_kernel(
    const float* __restrict__ Wq, const float* __restrict__ bq,
    const float* __restrict__ We, float* __restrict__ Wc, float* __restrict__ bc) {
  __shared__ float sWe[4][128];
  const int t = threadIdx.x;
  const int sub = t >> 7;
  const int tl = t & 127;
  const int i = blockIdx.x * 4 + sub;
  sWe[sub][tl] = We[i * 128 + tl];
  __syncthreads();
  float s = 0.f;
  for (int d = 0; d < 128; ++d) s = fmaf(Wq[tl * 128 + d], sWe[sub][d], s);
  Wc[tl * 128 + i] = s;
  if (tl == 0) {
    float sb = 0.f;
    for (int d = 0; d < 128; ++d) sb = fmaf(bq[d], sWe[sub][d], sb);
    bc[i] = sb;
  }
}

// ================= shared GEMM core: Out[row0..row0+7] = A-rows @ sW + bias =============
__device__ __forceinline__ void gemm_core(
    const float* __restrict__ A, const f32x4* __restrict__ sW,
    const float* __restrict__ bias, float* __restrict__ Out,
    size_t row0, int ostride, int tc) {
  const float* a0 = A + row0 * 128;
  f32x4 acc0[8], acc1[8];
#pragma unroll
  for (int r = 0; r < 8; ++r) { acc0[r] = (f32x4)(0.f); acc1[r] = (f32x4)(0.f); }
#pragma unroll 4
  for (int k4 = 0; k4 < 32; ++k4) {
    f32x4 a[8];
#pragma unroll
    for (int r = 0; r < 8; ++r)
      a[r] = *reinterpret_cast<const f32x4*>(a0 + r * 128 + k4 * 4);
#pragma unroll
    for (int kk = 0; kk < 4; ++kk) {
      const f32x4 w0 = sW[(k4 * 4 + kk) * 32 + tc * 2];
      const f32x4 w1 = sW[(k4 * 4 + kk) * 32 + tc * 2 + 1];
#pragma unroll
      for (int r = 0; r < 8; ++r) {
        const float av = a[r][kk];
        acc0[r] += av * w0;
        acc1[r] += av * w1;
      }
    }
  }
  const f32x4 b0 = reinterpret_cast<const f32x4*>(bias)[tc * 2];
  const f32x4 b1 = reinterpret_cast<const f32x4*>(bias)[tc * 2 + 1];
#pragma unroll
  for (int r = 0; r < 8; ++r) {
    f32x4* outp = reinterpret_cast<f32x4*>(Out + (row0 + r) * (size_t)ostride + tc * 8);
    outp[0] = acc0[r] + b0;
    outp[1] = acc1[r] + b1;
  }
}

// ============ MEGA kernel: 4 GEMMs + per-graph CSR + nmap init + pwn, ONE launch ========
// blocks [0,1024): node GEMMs   [1024,1088): per-graph CSR   [1088,1120): init   1120: pwn
__global__ __launch_bounds__(512) void mega_kernel(
    const float* __restrict__ x,
    const float* __restrict__ Wq, const float* __restrict__ bq, float* __restrict__ q,
    const float* __restrict__ Wk, const float* __restrict__ bk,
    const float* __restrict__ Wv, const float* __restrict__ bv, float* __restrict__ kv,
    const float* __restrict__ Wc, const float* __restrict__ bc, float* __restrict__ qw,
    const int* __restrict__ srcArr, const int* __restrict__ dstArr,
    int* __restrict__ offs, long long* __restrict__ srt,
    const float* __restrict__ pool_w, float* __restrict__ pwn,
    int* __restrict__ nmap, float* __restrict__ bn2) {
  __shared__ __align__(16) char smem[65536];
  const int blk = blockIdx.x;
  const int t = threadIdx.x;

  if (blk < 1024) {                       // ---- GEMM ----
    f32x4* sW = reinterpret_cast<f32x4*>(smem);
    const int which = blk >> 8;
    const int bid = blk & 255;
    const float* W; const float* bias; float* Out; int ostride = 128;
    if (which == 0)      { W = Wq; bias = bq; Out = q; }
    else if (which == 1) { W = Wk; bias = bk; Out = kv;       ostride = 256; }
    else if (which == 2) { W = Wv; bias = bv; Out = kv + 128; ostride = 256; }
    else                 { W = Wc; bias = bc; Out = qw; }
    const f32x4* W4 = reinterpret_cast<const f32x4*>(W);
#pragma unroll
    for (int i = 0; i < 8; ++i) sW[t + i * 512] = W4[t + i * 512];
    __syncthreads();
    gemm_core(x, sW, bias, Out, (size_t)bid * 256 + (t >> 4) * 8, ostride, t & 15);
  } else if (blk < 1088) {                // ---- per-graph CSR (LDS count+scan+scatter) ----
    int* cnt = reinterpret_cast<int*>(smem);          // [1024]
    int* aux = cnt + 1024;                            // [512]
    const int g = blk - 1024;
    const int ebase = g * 16384;
    cnt[t] = 0; cnt[t + 512] = 0;
    __syncthreads();
#pragma unroll 4
    for (int j = 0; j < 32; ++j) {
      const int e = ebase + j * 512 + t;
      atomicAdd(&cnt[dstArr[e] & 1023], 1);
    }
    __syncthreads();
    const int two0 = cnt[2 * t], two1 = cnt[2 * t + 1];
    const int part = two0 + two1;
    aux[t] = part;
    __syncthreads();
    for (int d = 1; d < 512; d <<= 1) {
      const int add = (t >= d) ? aux[t - d] : 0;
      __syncthreads();
      aux[t] += add;
      __syncthreads();
    }
    const int excl2 = aux[t] - part;      // exclusive prefix over node pairs
    __syncthreads();
    offs[g * 1024 + 2 * t]     = ebase + excl2;
    offs[g * 1024 + 2 * t + 1] = ebase + excl2 + two0;
    cnt[2 * t] = excl2;
    cnt[2 * t + 1] = excl2 + two0;
    if (g == 0 && t == 0) offs[NODES] = NEDGE;
    __syncthreads();
#pragma unroll 4
    for (int j = 0; j < 32; ++j) {
      const int e = ebase + j * 512 + t;
      const int d = dstArr[e] & 1023;
      const int pos = atomicAdd(&cnt[d], 1);
      srt[ebase + pos] = ((long long)srcArr[e] << 32) | (unsigned)e;
    }
  } else if (blk < 1120) {                // ---- nmap init (+bn2) ----
    const int base = ((blk - 1088) * 512 + t) * 4;
    nmap[base] = -1; nmap[base + 1] = -1; nmap[base + 2] = -1; nmap[base + 3] = -1;
    if (blk == 1088 && t < 256) bn2[t] = 0.f;   // bnsum[128]+bnsq[128]
  } else {                                // ---- pwn ----
    float* red = reinterpret_cast<float*>(smem);
    if (t < 128) {
      const float vv = pool_w[t];
      red[t] = vv * vv;
    }
    __syncthreads();
    for (int d = 64; d > 0; d >>= 1) {
      if (t < d) red[t] += red[t + d];
      __syncthreads();
    }
    if (t < 128) pwn[t] = pool_w[t] * rsqrtf(red[0]);
  }
}

// ====== final: outc = relu(agge@We + x@Ws + be + bs + aggv); score epilogue ======
__global__ __launch_bounds__(256) void gemm_final2(
    const float* __restrict__ agge, const float* __restrict__ We,
    const float* __restrict__ x,    const float* __restrict__ Ws,
    const float* __restrict__ be,   const float* __restrict__ bs,
    const float* __restrict__ aggv, const float* __restrict__ pwn,
    float* __restrict__ outc, float* __restrict__ score) {
  __shared__ f32x4 sW[128 * 32];
  const int t = threadIdx.x;
  const int tc = t & 15;
  const size_t row0 = (size_t)blockIdx.x * 128 + (t >> 4) * 8;
  f32x4 acc0[8], acc1[8];
#pragma unroll
  for (int r = 0; r < 8; ++r) { acc0[r] = (f32x4)(0.f); acc1[r] = (f32x4)(0.f); }

#pragma unroll
  for (int phase = 0; phase < 2; ++phase) {
    const float* W = phase ? Ws : We;
    const float* A = phase ? x : agge;
    const f32x4* W4 = reinterpret_cast<const f32x4*>(W);
    if (phase) __syncthreads();
#pragma unroll
    for (int i = 0; i < 16; ++i) sW[t + i * 256] = W4[t + i * 256];
    __syncthreads();
    const float* a0 = A + row0 * 128;
#pragma unroll 4
    for (int k4 = 0; k4 < 32; ++k4) {
      f32x4 a[8];
#pragma unroll
      for (int r = 0; r < 8; ++r)
        a[r] = *reinterpret_cast<const f32x4*>(a0 + r * 128 + k4 * 4);
#pragma unroll
      for (int kk = 0; kk < 4; ++kk) {
        const f32x4 w0 = sW[(k4 * 4 + kk) * 32 + tc * 2];
        const f32x4 w1 = sW[(k4 * 4 + kk) * 32 + tc * 2 + 1];
#pragma unroll
        for (int r = 0; r < 8; ++r) {
          const float av = a[r][kk];
          acc0[r] += av * w0;
          acc1[r] += av * w1;
        }
      }
    }
  }
  const f32x4 b0 = reinterpret_cast<const f32x4*>(be)[tc * 2] +
                   reinterpret_cast<const f32x4*>(bs)[tc * 2];
  const f32x4 b1 = reinterpret_cast<const f32x4*>(be)[tc * 2 + 1] +
                   reinterpret_cast<const f32x4*>(bs)[tc * 2 + 1];
  const f32x4 p0 = reinterpret_cast<const f32x4*>(pwn)[tc * 2];
  const f32x4 p1 = reinterpret_cast<const f32x4*>(pwn)[tc * 2 + 1];
#pragma unroll
  for (int r = 0; r < 8; ++r) {
    const f32x4 v0 = reinterpret_cast<const f32x4*>(aggv + (row0 + r) * 128 + tc * 8)[0];
    const f32x4 v1 = reinterpret_cast<const f32x4*>(aggv + (row0 + r) * 128 + tc * 8)[1];
    f32x4 o0 = acc0[r] + b0 + v0;
    f32x4 o1 = acc1[r] + b1 + v1;
#pragma unroll
    for (int c = 0; c < 4; ++c) { o0[c] = fmaxf(o0[c], 0.f); o1[c] = fmaxf(o1[c], 0.f); }
    f32x4* outp = reinterpret_cast<f32x4*>(outc + (row0 + r) * 128 + tc * 8);
    outp[0] = o0; outp[1] = o1;
    float sp = dotv(o0, p0) + dotv(o1, p1);
#pragma unroll
    for (int d = 1; d < 16; d <<= 1) sp += __shfl_xor(sp, d, 16);
    if (tc == 0) score[row0 + r] = tanhf(sp);
  }
}

// ========== fused attention v8: 2x32-lane groups, fully-contiguous 512B row loads ==========
// Per edge: 3 VMEM (k,v,ea) instead of 6 half-line loads; 2 edges/group in flight.
__global__ __launch_bounds__(256) void attn_v8(
    const float* __restrict__ q, const float* __restrict__ kv,
    const float* __restrict__ qw, const float* __restrict__ ea,
    const float* __restrict__ be, const long long* __restrict__ srt,
    const int* __restrict__ offs, float* __restrict__ aggv,
    float* __restrict__ agge) {
  int b = blockIdx.x;
  b = (b & 7) * 2048 + (b >> 3);                        // XCD-bijective swizzle (16384%8==0)
  const int wid = b * 4 + (threadIdx.x >> 6);
  const int lane = threadIdx.x & 63;
  const int g = lane >> 5;        // edge-group 0..1 (32 lanes each)
  const int l = lane & 31;        // lane owns dims 4l..4l+3
  const f32x4* q4  = reinterpret_cast<const f32x4*>(q)  + (size_t)wid * 32;
  const f32x4* qw4 = reinterpret_cast<const f32x4*>(qw) + (size_t)wid * 32;
  const f32x4* be4 = reinterpret_cast<const f32x4*>(be);
  const f32x4 qv  = q4[l];
  const f32x4 qwv = qw4[l];
  const float SCALE = 0.08838834764831845f;             // 1/sqrt(128)
  float qbe = dotv(qv, be4[l]);
  qbe = row16_sum(qbe);
  qbe += __shfl_xor(qbe, 16, 64);
  const float qbeS = qbe * SCALE;

  const f32x4* kv4 = reinterpret_cast<const f32x4*>(kv);
  const f32x4* ea4 = reinterpret_cast<const f32x4*>(ea);
  float denom = 0.f;
  f32x4 av = (f32x4)(0.f), ag = (f32x4)(0.f);
  const int e0 = offs[wid], e1 = offs[wid + 1];
  int p = e0 + g;
  long long pkA = 0, pkB = 0;
  if (p < e1) {
    pkA = ntloadll(srt + p);
    pkB = ((p + 2) < e1) ? ntloadll(srt + p + 2) : pkA;
  }
  while (p < e1) {
    const bool h2 = (p + 2) < e1;
    const int pn = p + 4;
    long long nA = 0, nB = 0;
    if (pn < e1) {                        // prefetch next iteration's srt pair
      nA = ntloadll(srt + pn);
      nB = ((pn + 2) < e1) ? ntloadll(srt + pn + 2) : nA;
    }
    const int eA = (int)pkA, sA = (int)(pkA >> 32);
    const int eB = (int)pkB, sB = (int)(pkB >> 32);
    const f32x4* kvA = kv4 + (size_t)sA * 64 + l;
    const f32x4* kvB = kv4 + (size_t)sB * 64 + l;
    const f32x4 kA = kvA[0], vA = kvA[32];              // 32 lanes x 16B = 512B contiguous
    const f32x4 kB = kvB[0], vB = kvB[32];
    const f32x4 fA = ntload4(ea4 + (size_t)eA * 32 + l);
    const f32x4 fB = ntload4(ea4 + (size_t)eB * 32 + l);
    float pA = dotv(qv, kA) + dotv(qwv, fA);
    float pB = dotv(qv, kB) + dotv(qwv, fB);
    pA = row16_sum(pA); pA += __shfl_xor(pA, 16, 64);   // 32-lane sum
    pB = row16_sum(pB); pB += __shfl_xor(pB, 16, 64);
    const float wA = __expf(fmaf(pA, SCALE, qbeS));
    const float wB = h2 ? __expf(fmaf(pB, SCALE, qbeS)) : 0.f;
    denom += wA + wB;
    av += wA * vA + wB * vB;
    ag += wA * fA + wB * fB;
    pkA = nA; pkB = nB; p = pn;
  }
  // cross-group combine (xor 32)
  denom += __shfl_xor(denom, 32, 64);
#pragma unroll
  for (int c = 0; c < 4; ++c) {
    av[c] += __shfl_xor(av[c], 32, 64);
    ag[c] += __shfl_xor(ag[c], 32, 64);
  }
  if (g == 0) {
    const float inv = 1.f / (denom + 1e-16f);
    f32x4* aggv4 = reinterpret_cast<f32x4*>(aggv) + (size_t)wid * 32;
    f32x4* agge4 = reinterpret_cast<f32x4*>(agge) + (size_t)wid * 32;
    aggv4[l] = av * inv;                                // 512B coalesced
    agge4[l] = ag * inv;
  }
}

// ===== fused top-k (bitonic, desc, tie->lower idx) + xp gather + BN partial sums =====
__global__ __launch_bounds__(1024) void topkxp_kernel(
    const float* __restrict__ score, const float* __restrict__ outc,
    float* __restrict__ y, float* __restrict__ batchf, int* __restrict__ nmap,
    float* __restrict__ bnsum, float* __restrict__ bnsq) {
  __shared__ float ss[1024];
  __shared__ int si[1024];
  const int b = blockIdx.x, t = threadIdx.x;
  ss[t] = score[b * 1024 + t];
  si[t] = t;
  __syncthreads();
  for (int size = 2; size <= 1024; size <<= 1) {
    for (int stride = size >> 1; stride > 0; stride >>= 1) {
      const int j = t ^ stride;
      if (j > t) {
        const float s1 = ss[t], s2 = ss[j];
        const int i1 = si[t], i2 = si[j];
        const bool bj = (s2 > s1) || (s2 == s1 && i2 < i1);
        const bool dir = ((t & size) == 0);
        if (dir ? bj : !bj) { ss[t] = s2; ss[j] = s1; si[t] = i2; si[j] = i1; }
      }
      __syncthreads();
    }
  }
  if (t < TOPK) {
    batchf[b * TOPK + t] = (float)b;
    nmap[b * 1024 + si[t]] = b * TOPK + t;
  }
  __syncthreads();
  // xp phase: 512 rows x 128 cols, 1024 threads (8 row-slots x 128 cols)
  const int c = t & 127;
  const int rbase = t >> 7;              // 0..7
  float s = 0.f, s2 = 0.f;
  for (int i = 0; i < 64; ++i) {
    const int r = rbase + 8 * i;         // 0..511
    const int gnode = b * 1024 + si[r];
    const float val = outc[(size_t)gnode * DIM + c] * ss[r];
    y[((size_t)b * TOPK + r) * DIM + c] = val;
    s += val;
    s2 = fmaf(val, val, s2);
  }
  atomicAdd(&bnsum[c], s);
  atomicAdd(&bnsq[c], s2);
}

// ==== fused: edge remap + valid + masked edge_attr  AND  BN apply (block-range split) ====
#define EF_BLOCKS (NEDGE / 8)            // 131072
#define BN_BLOCKS ((BKR * 32) / 256)     // 4096
__global__ __launch_bounds__(256) void tail_kernel(
    const int* __restrict__ srcArr, const int* __restrict__ dstArr,
    const int* __restrict__ nm, const float* __restrict__ ea,
    float* __restrict__ nei, float* __restrict__ validf, float* __restrict__ nea,
    float* __restrict__ y, const float* __restrict__ bnsum, const float* __restrict__ bnsq,
    const float* __restrict__ gamma, const float* __restrict__ beta) {
  const int blk = blockIdx.x;
  const int t = threadIdx.x;
  if (blk < EF_BLOCKS) {                 // ---- efnea ----
    const int row = blk * 8 + (t >> 5);
    const int lane = t & 31;
    const int ns = nm[srcArr[row]];
    const int nd = nm[dstArr[row]];
    const bool val = (ns >= 0) && (nd >= 0);
    if (lane == 0) {
      nei[row] = val ? (float)ns : -1.f;
      nei[NEDGE + row] = val ? (float)nd : -1.f;
      validf[row] = val ? 1.f : 0.f;
    }
    const size_t i4 = (size_t)row * 32 + lane;
    f32x4 v = (f32x4)(0.f);
    if (val) v = ntload4(reinterpret_cast<const f32x4*>(ea) + i4);
    ntstore4(reinterpret_cast<f32x4*>(nea) + i4, v);
  } else {                               // ---- BN apply ----
    const size_t i4 = (size_t)(blk - EF_BLOCKS) * 256 + t;   // BKR*32 float4s
    const int c4 = (int)(i4 & 31);
    f32x4 a, c;
#pragma unroll
    for (int j = 0; j < 4; ++j) {
      const int col = c4 * 4 + j;
      const float mu = bnsum[col] * (1.f / BKR);
      const float var = bnsq[col] * (1.f / BKR) - mu * mu;
      const float aa = gamma[col] * rsqrtf(var + 1e-5f);
      a[j] = aa;
      c[j] = beta[col] - mu * aa;
    }
    f32x4 v = reinterpret_cast<f32x4*>(y)[i4];
#pragma unroll
    for (int j = 0; j < 4; ++j) v[j] = fmaf(v[j], a[j], c[j]);
    reinterpret_cast<f32x4*>(y)[i4] = v;
  }
}

// ---------------- launch ----------------
extern "C" void kernel_launch(void* const* d_in, const int* in_sizes, int n_in,
                              void* d_out, int out_size, void* d_ws, size_t ws_size,
                              hipStream_t stream) {
  const float* x     = (const float*)d_in[0];
  const int*   eidx  = (const int*)d_in[1];
  const float* eattr = (const float*)d_in[2];
  const float* Wq = (const float*)d_in[4];  const float* bq = (const float*)d_in[5];
  const float* Wk = (const float*)d_in[6];  const float* bk = (const float*)d_in[7];
  const float* Wv = (const float*)d_in[8];  const float* bv = (const float*)d_in[9];
  const float* We = (const float*)d_in[10]; const float* be = (const float*)d_in[11];
  const float* Ws = (const float*)d_in[12]; const float* bs = (const float*)d_in[13];
  const float* pool_w = (const float*)d_in[14];
  const float* gamma  = (const float*)d_in[15];
  const float* beta   = (const float*)d_in[16];

  const int* srcArr = eidx;
  const int* dstArr = eidx + NEDGE;

  float* out = (float*)d_out;
  // output layout (floats)
  float* y      = out;                                   // BKR*128
  float* nei    = out + (size_t)BKR * DIM;               // 2*NEDGE
  float* nea    = nei + 2 * (size_t)NEDGE;               // NEDGE*128
  float* batchf = nea + (size_t)NEDGE * DIM;             // BKR
  float* validf = batchf + BKR;                          // NEDGE

  // big node arrays staged inside the (not-yet-written) nea region: 7 x NM = 224MB
  float* q    = nea + 0 * NM;
  float* kv   = nea + 1 * NM;   // 2*NM (k|v interleaved, 256 floats/row)
  float* qw   = nea + 3 * NM;
  float* aggv = nea + 4 * NM;
  float* agge = nea + 5 * NM;
  float* outc = nea + 6 * NM;

  // workspace layout (small)
  char* w = (char*)d_ws;
  size_t off = 0;
  float* score= (float*)(w + off); off += (size_t)NODES * 4;
  float* pwn  = (float*)(w + off); off += 128 * 4;
  float* Wc   = (float*)(w + off); off += 128 * 128 * 4;
  float* bc   = (float*)(w + off); off += 128 * 4;
  float* bnsum= (float*)(w + off); off += 128 * 4;
  float* bnsq = (float*)(w + off); off += 128 * 4;
  int* offs   = (int*)(w + off); off += ((size_t)NODES + 8) * 4;
  int* nmap   = (int*)(w + off); off += (size_t)NODES * 4;
  long long* srt = (long long*)(w + off); off += (size_t)NEDGE * 8;

  // 1) Wc precompute (must precede mega's which==3 GEMM that reads Wc)
  wc_kernel<<<32, 512, 0, stream>>>(Wq, bq, We, Wc, bc);

  // 2) mega: 4 GEMMs + per-graph CSR + nmap init + pwn in one launch
  mega_kernel<<<1121, 512, 0, stream>>>(
      x, Wq, bq, q, Wk, bk, Wv, bv, kv, Wc, bc, qw,
      srcArr, dstArr, offs, srt, pool_w, pwn, nmap, (float*)bnsum);

  // 3) fused attention on raw edge_attr (contiguous 512B row loads)
  attn_v8<<<NODES / 4, 256, 0, stream>>>(q, kv, qw, eattr, be, srt, offs, aggv, agge);

  // 4) final conv output (+ fused skip GEMM) + score
  gemm_final2<<<NODES / 128, 256, 0, stream>>>(agge, We, x, Ws, be, bs, aggv, pwn,
                                               outc, score);

  // 5) top-k + xp gather + BN partial sums (reads outc before staging overwrite)
  topkxp_kernel<<<NB, 1024, 0, stream>>>(score, outc, y, batchf, nmap, bnsum, bnsq);

  // 6) tail: edge remap + masked edge_attr + BN apply (one launch)
  tail_kernel<<<EF_BLOCKS + BN_BLOCKS, 256, 0, stream>>>(
      srcArr, dstArr, nmap, eattr, nei, validf, nea,
      y, bnsum, bnsq, gamma, beta);
}